// Round 1
// baseline (2317.629 us; speedup 1.0000x reference)
//
#include <hip/hip_runtime.h>
#include <hip/hip_bf16.h>

// ---------------------------------------------------------------------------
// Net_83674552861196: conv(3->10,5x5,p1) -> BN(batch stats) -> relu -> pool2
//   -> conv(10->20,5x5,p1) -> relu -> pool2 -> feat[4096,3920]
//   -> gate (fc 3920->64 relu, fc 64->8, top2 softmax)
//   -> top-2 expert MLPs (3920->128->64->1000) combined by gate weights
//   -> log_softmax(|out|)
// Exploits: (a) BN scale>0 => pool commutes with BN+relu, so pass1 pools RAW
// conv1 output (stored bf16) while accumulating BN stats; (b) only top-2
// experts contribute (gates are exactly 0 elsewhere) => grouped expert GEMMs.
// All heavy math fp32 this round (baseline correctness).
// ---------------------------------------------------------------------------

#define TPB 256

// ---------------- K1: conv1 + raw-maxpool + BN statistics ------------------
__global__ __launch_bounds__(TPB) void k_conv1(
    const float* __restrict__ x, const float* __restrict__ w1c,
    const float* __restrict__ b1c, __hip_bfloat16* __restrict__ pool1,
    float* __restrict__ stats /* sum[10], sumsq[10] */)
{
  __shared__ float simg[12288];           // 3x64x64 image, 48 KB
  const int tid = threadIdx.x;
  const int n = blockIdx.x;
  {
    const float4* s = (const float4*)(x + (size_t)n * 12288);
    float4* d = (float4*)simg;
#pragma unroll
    for (int i = 0; i < 12; i++) d[tid + 256 * i] = s[tid + 256 * i];
  }
  __syncthreads();

  float ts[10], tss[10];
#pragma unroll
  for (int c = 0; c < 10; c++) { ts[c] = 0.f; tss[c] = 0.f; }

  for (int p = tid; p < 961; p += TPB) {   // pool output 31x31
    const int ph = p / 31, pw = p - 31 * ph;
    float acc[4][10];
#pragma unroll
    for (int i = 0; i < 4; i++)
#pragma unroll
      for (int c = 0; c < 10; c++) acc[i][c] = 0.f;

    for (int ic = 0; ic < 3; ic++) {
      float pat[6][6];
#pragma unroll
      for (int rr = 0; rr < 6; rr++) {
        const int r = 2 * ph - 1 + rr;
        const bool rok = (r >= 0) && (r < 64);
#pragma unroll
        for (int cc = 0; cc < 6; cc++) {
          const int cI = 2 * pw - 1 + cc;
          pat[rr][cc] = (rok && (cI >= 0) && (cI < 64))
                            ? simg[ic * 4096 + (r << 6) + cI] : 0.f;
        }
      }
      const float* wp = w1c + ic * 25;     // w[oc][ic][kh][kw], static offsets -> s_load
#pragma unroll
      for (int kh = 0; kh < 5; kh++)
#pragma unroll
        for (int kw = 0; kw < 5; kw++) {
          const float p00 = pat[kh][kw],     p01 = pat[kh][kw + 1];
          const float p10 = pat[kh + 1][kw], p11 = pat[kh + 1][kw + 1];
#pragma unroll
          for (int oc = 0; oc < 10; oc++) {
            const float wv = wp[oc * 75 + kh * 5 + kw];
            acc[0][oc] = fmaf(wv, p00, acc[0][oc]);
            acc[1][oc] = fmaf(wv, p01, acc[1][oc]);
            acc[2][oc] = fmaf(wv, p10, acc[2][oc]);
            acc[3][oc] = fmaf(wv, p11, acc[3][oc]);
          }
        }
    }
#pragma unroll
    for (int oc = 0; oc < 10; oc++) {
      const float bb = b1c[oc];
      const float y0 = acc[0][oc] + bb, y1 = acc[1][oc] + bb;
      const float y2 = acc[2][oc] + bb, y3 = acc[3][oc] + bb;
      ts[oc]  += (y0 + y1) + (y2 + y3);
      tss[oc] += y0 * y0 + y1 * y1 + y2 * y2 + y3 * y3;
      const float m = fmaxf(fmaxf(y0, y1), fmaxf(y2, y3));
      pool1[((size_t)(n * 10 + oc)) * 961 + p] = __float2bfloat16(m);
    }
  }

  __shared__ float sred[20];
  if (tid < 20) sred[tid] = 0.f;
  __syncthreads();
#pragma unroll
  for (int c = 0; c < 10; c++) {
    atomicAdd(&sred[c], ts[c]);
    atomicAdd(&sred[10 + c], tss[c]);
  }
  __syncthreads();
  if (tid < 20) atomicAdd(&stats[tid], sred[tid]);
}

// ---------------- K2: finalize BN scale/shift ------------------------------
__global__ void k_bnfin(const float* __restrict__ bng,
                        const float* __restrict__ bnb,
                        float* __restrict__ stats)
{
  const int c = threadIdx.x;
  if (c < 10) {
    const float Ninv = 1.f / (4096.f * 3844.f);
    const float mean = stats[c] * Ninv;
    const float var = stats[10 + c] * Ninv - mean * mean;
    const float sc = bng[c] * rsqrtf(var + 1e-5f);
    stats[20 + c] = sc;
    stats[30 + c] = bnb[c] - mean * sc;
  }
}

// ---------------- K3: BN+relu on pooled conv1, conv2 + pool2 -> feat -------
__global__ __launch_bounds__(TPB) void k_conv2(
    const __hip_bfloat16* __restrict__ pool1, const float* __restrict__ stats,
    const float* __restrict__ w2c, const float* __restrict__ b2c,
    float* __restrict__ feat)
{
  __shared__ float sp[10 * 1089];          // 10 x 33 x 33 zero-padded, 43.6 KB
  __shared__ float ssc[10], ssh[10];
  const int tid = threadIdx.x;
  const int n = blockIdx.x;
  if (tid < 10) { ssc[tid] = stats[20 + tid]; ssh[tid] = stats[30 + tid]; }
  for (int i = tid; i < 10890; i += TPB) sp[i] = 0.f;
  __syncthreads();
  const __hip_bfloat16* src = pool1 + (size_t)n * 9610;
  for (int i = tid; i < 9610; i += TPB) {
    const int ic = i / 961, rem = i - ic * 961;
    const int r = rem / 31, c = rem - r * 31;
    float v = __bfloat162float(src[i]);
    v = fmaxf(fmaf(v, ssc[ic], ssh[ic]), 0.f);
    sp[ic * 1089 + (r + 1) * 33 + (c + 1)] = v;
  }
  __syncthreads();

  if (tid < 196) {                         // pool2 output 14x14 (skips row/col 28)
    const int qh = tid / 14, qw = tid - 14 * (tid / 14);
    for (int half = 0; half < 2; half++) { // oc in two groups of 10 (VGPR control)
      float acc[4][10];
#pragma unroll
      for (int i = 0; i < 4; i++)
#pragma unroll
        for (int j = 0; j < 10; j++) acc[i][j] = b2c[half * 10 + j];
      for (int ic = 0; ic < 10; ic++) {
        float pat[6][6];
        const float* base = &sp[ic * 1089 + 2 * qh * 33 + 2 * qw];
#pragma unroll
        for (int rr = 0; rr < 6; rr++)
#pragma unroll
          for (int cc = 0; cc < 6; cc++) pat[rr][cc] = base[rr * 33 + cc];
        const float* wp = w2c + (half * 10) * 250 + ic * 25;
#pragma unroll
        for (int kh = 0; kh < 5; kh++)
#pragma unroll
          for (int kw = 0; kw < 5; kw++) {
            const float p00 = pat[kh][kw],     p01 = pat[kh][kw + 1];
            const float p10 = pat[kh + 1][kw], p11 = pat[kh + 1][kw + 1];
#pragma unroll
            for (int j = 0; j < 10; j++) {
              const float wv = wp[j * 250 + kh * 5 + kw];
              acc[0][j] = fmaf(wv, p00, acc[0][j]);
              acc[1][j] = fmaf(wv, p01, acc[1][j]);
              acc[2][j] = fmaf(wv, p10, acc[2][j]);
              acc[3][j] = fmaf(wv, p11, acc[3][j]);
            }
          }
      }
      float* fdst = feat + (size_t)n * 3920 + (half * 10) * 196 + tid;
#pragma unroll
      for (int j = 0; j < 10; j++) {
        const float m = fmaxf(
            fmaxf(fmaxf(acc[0][j], acc[1][j]), fmaxf(acc[2][j], acc[3][j])), 0.f);
        fdst[j * 196] = m;               // feat layout [n][c][qh][qw]
      }
    }
  }
}

// ---------------- K4a: gate fc1 partial GEMM (atomic K-split) --------------
__global__ __launch_bounds__(TPB) void k_gate1(
    const float* __restrict__ feat, const float* __restrict__ gw1,
    float* __restrict__ graw)
{
  __shared__ float sf[64 * 113];
  __shared__ float sw[64 * 113];
  const int tid = threadIdx.x;
  const int r0 = blockIdx.x * 64;
  const int kz = blockIdx.y;
  const int ty = tid >> 4, tx = tid & 15;
  float acc[4][4] = {{0.f}};
  for (int c = kz; c < 35; c += 4) {
    const int k0 = c * 112;
    for (int i = tid; i < 1792; i += TPB) {
      const int row = i / 28, c4 = (i - row * 28) * 4;
      float4 v = *(const float4*)(feat + (size_t)(r0 + row) * 3920 + k0 + c4);
      float* d = &sf[row * 113 + c4];
      d[0] = v.x; d[1] = v.y; d[2] = v.z; d[3] = v.w;
      float4 u = *(const float4*)(gw1 + (size_t)row * 3920 + k0 + c4);
      float* e = &sw[row * 113 + c4];
      e[0] = u.x; e[1] = u.y; e[2] = u.z; e[3] = u.w;
    }
    __syncthreads();
    for (int k = 0; k < 112; k++) {
      float a_[4], w_[4];
#pragma unroll
      for (int i = 0; i < 4; i++) a_[i] = sf[(ty * 4 + i) * 113 + k];
#pragma unroll
      for (int j = 0; j < 4; j++) w_[j] = sw[(tx * 4 + j) * 113 + k];
#pragma unroll
      for (int i = 0; i < 4; i++)
#pragma unroll
        for (int j = 0; j < 4; j++) acc[i][j] = fmaf(a_[i], w_[j], acc[i][j]);
    }
    __syncthreads();
  }
#pragma unroll
  for (int i = 0; i < 4; i++)
#pragma unroll
    for (int j = 0; j < 4; j++)
      atomicAdd(&graw[(size_t)(r0 + ty * 4 + i) * 64 + tx * 4 + j], acc[i][j]);
}

// ---------------- K4b: gate logits + top2 softmax + expert counts ----------
__global__ __launch_bounds__(TPB) void k_gate2(
    const float* __restrict__ graw, const float* __restrict__ gb1,
    const float* __restrict__ gw2, const float* __restrict__ gb2,
    int* __restrict__ sel0, int* __restrict__ sel1,
    float* __restrict__ wt0, float* __restrict__ wt1, int* __restrict__ counts)
{
  __shared__ float sw2[512], sb1[64], sb2[8];
  const int tid = threadIdx.x;
  for (int i = tid; i < 512; i += TPB) sw2[i] = gw2[i];
  if (tid < 64) sb1[tid] = gb1[tid];
  if (tid < 8) sb2[tid] = gb2[tid];
  __syncthreads();
  const int r = blockIdx.x * TPB + tid;
  float l[8];
#pragma unroll
  for (int c = 0; c < 8; c++) l[c] = sb2[c];
  const float* gr = graw + (size_t)r * 64;
  for (int k = 0; k < 64; k++) {
    const float hv = fmaxf(gr[k] + sb1[k], 0.f);
#pragma unroll
    for (int c = 0; c < 8; c++) l[c] = fmaf(hv, sw2[c * 64 + k], l[c]);
  }
  float v0 = -1e30f, v1 = -1e30f; int i0 = 0, i1 = 0;
#pragma unroll
  for (int c = 0; c < 8; c++) {
    const float lv = l[c];
    if (lv > v0) { v1 = v0; i1 = i0; v0 = lv; i0 = c; }
    else if (lv > v1) { v1 = lv; i1 = c; }
  }
  const float e1 = expf(v1 - v0);
  const float inv = 1.f / (1.f + e1);
  sel0[r] = i0; sel1[r] = i1; wt0[r] = inv; wt1[r] = e1 * inv;
  atomicAdd(&counts[i0], 1);
  atomicAdd(&counts[i1], 1);
}

// ---------------- K5: padded offsets + entry-list init ---------------------
__global__ void k_prep(int* __restrict__ hdrI, int* __restrict__ entrow)
{
  const int tid = threadIdx.x;
  if (tid == 0) {
    int run = 0;
    for (int e = 0; e < 8; e++) {
      const int c = hdrI[e];                 // count
      const int pc = (c + 31) & ~31;         // pad to 32
      hdrI[16 + e] = pc;                     // pcnt
      hdrI[24 + e] = run;                    // poff
      run += pc;
    }
    hdrI[32] = run;
  }
  if (tid >= 8 && tid < 16) hdrI[tid] = 0;   // cursors
  for (int i = tid; i < 8448; i += TPB) entrow[i] = -1;
}

// ---------------- K5b: scatter rows to expert entry lists ------------------
__global__ void k_scatter(const int* __restrict__ sel0, const int* __restrict__ sel1,
                          int* __restrict__ hdrI, int* __restrict__ entrow,
                          int* __restrict__ p0, int* __restrict__ p1)
{
  const int r = blockIdx.x * TPB + threadIdx.x;
  const int e0 = sel0[r];
  int pos = atomicAdd(&hdrI[8 + e0], 1) + hdrI[24 + e0];
  entrow[pos] = r; p0[r] = pos;
  const int e1 = sel1[r];
  pos = atomicAdd(&hdrI[8 + e1], 1) + hdrI[24 + e1];
  entrow[pos] = r; p1[r] = pos;
}

// ---------------- K6: grouped expert fc1+fc2 -------------------------------
__global__ __launch_bounds__(TPB) void k_fc12(
    const float* __restrict__ feat, const float* __restrict__ ew1,
    const float* __restrict__ eb1, const float* __restrict__ ew2,
    const float* __restrict__ eb2, const int* __restrict__ hdrI,
    const int* __restrict__ entrow, float* __restrict__ h2buf)
{
  __shared__ float smem[18080];   // fc1: sf 32x113 | sw 128x113 ; fc2 reuse
  __shared__ int srow[32];
  const int e = blockIdx.y;
  const int pcnt = hdrI[16 + e];
  if ((int)blockIdx.x * 32 >= pcnt) return;
  const int base = hdrI[24 + e] + blockIdx.x * 32;
  const int tid = threadIdx.x;
  if (tid < 32) srow[tid] = entrow[base + tid];
  float* sf = smem;
  float* sw = smem + 32 * 113;
  const float* w1p = ew1 + (size_t)e * 128 * 3920;
  const int ty = tid >> 5, tx = tid & 31;   // 8 row-groups x 32 out-groups
  float acc[4][4] = {{0.f}};
  __syncthreads();
  for (int c = 0; c < 35; c++) {
    const int k0 = c * 112;
    for (int i = tid; i < 3584; i += TPB) {         // w1 chunk 128x112
      const int row = i / 28, c4 = (i - row * 28) * 4;
      float4 u = *(const float4*)(w1p + (size_t)row * 3920 + k0 + c4);
      float* d = &sw[row * 113 + c4];
      d[0] = u.x; d[1] = u.y; d[2] = u.z; d[3] = u.w;
    }
    for (int i = tid; i < 896; i += TPB) {          // feat gather 32x112
      const int row = i / 28, c4 = (i - row * 28) * 4;
      const int rr = srow[row];
      float4 v = (rr >= 0)
          ? *(const float4*)(feat + (size_t)rr * 3920 + k0 + c4)
          : make_float4(0.f, 0.f, 0.f, 0.f);
      float* d = &sf[row * 113 + c4];
      d[0] = v.x; d[1] = v.y; d[2] = v.z; d[3] = v.w;
    }
    __syncthreads();
    for (int k = 0; k < 112; k++) {
      float a_[4], w_[4];
#pragma unroll
      for (int i = 0; i < 4; i++) a_[i] = sf[(ty * 4 + i) * 113 + k];
#pragma unroll
      for (int j = 0; j < 4; j++) w_[j] = sw[(tx * 4 + j) * 113 + k];
#pragma unroll
      for (int i = 0; i < 4; i++)
#pragma unroll
        for (int j = 0; j < 4; j++) acc[i][j] = fmaf(a_[i], w_[j], acc[i][j]);
    }
    __syncthreads();
  }
  // fc2 phase: h1 (relu) -> LDS, stage w2, 32x64 GEMM over K=128
  float* h1s = smem;              // 32 x 129
  float* w2s = smem + 4128;       // 64 x 129
  const float* b1p = eb1 + e * 128;
#pragma unroll
  for (int i = 0; i < 4; i++)
#pragma unroll
    for (int j = 0; j < 4; j++)
      h1s[(ty * 4 + i) * 129 + tx * 4 + j] =
          fmaxf(acc[i][j] + b1p[tx * 4 + j], 0.f);
  const float* w2p = ew2 + (size_t)e * 64 * 128;
  for (int i = tid; i < 2048; i += TPB) {
    const int row = i / 32, c4 = (i - row * 32) * 4;
    float4 u = *(const float4*)(w2p + row * 128 + c4);
    float* d = &w2s[row * 129 + c4];
    d[0] = u.x; d[1] = u.y; d[2] = u.z; d[3] = u.w;
  }
  __syncthreads();
  float acc2[4][2] = {{0.f}};
  for (int k = 0; k < 128; k++) {
    float a_[4];
#pragma unroll
    for (int i = 0; i < 4; i++) a_[i] = h1s[(ty * 4 + i) * 129 + k];
    const float w0_ = w2s[(tx * 2 + 0) * 129 + k];
    const float w1_ = w2s[(tx * 2 + 1) * 129 + k];
#pragma unroll
    for (int i = 0; i < 4; i++) {
      acc2[i][0] = fmaf(a_[i], w0_, acc2[i][0]);
      acc2[i][1] = fmaf(a_[i], w1_, acc2[i][1]);
    }
  }
  const float* b2p = eb2 + e * 64;
#pragma unroll
  for (int i = 0; i < 4; i++)
#pragma unroll
    for (int j = 0; j < 2; j++)
      h2buf[(size_t)(base + ty * 4 + i) * 64 + tx * 2 + j] =
          fmaxf(acc2[i][j] + b2p[tx * 2 + j], 0.f);
}

// ---------------- K6b: grouped expert fc3 -> eo ----------------------------
__global__ __launch_bounds__(TPB) void k_fc3(
    const float* __restrict__ h2buf, const float* __restrict__ ew3,
    const float* __restrict__ eb3, const int* __restrict__ hdrI,
    float* __restrict__ eo)
{
  __shared__ float h2s[32 * 65];
  __shared__ float w3s[128 * 65];
  const int e = blockIdx.y;
  const int pcnt = hdrI[16 + e];
  if ((int)blockIdx.x * 32 >= pcnt) return;
  const int base = hdrI[24 + e] + blockIdx.x * 32;
  const int tid = threadIdx.x;
  for (int i = tid; i < 512; i += TPB) {
    const int row = i / 16, c4 = (i - row * 16) * 4;
    float4 v = *(const float4*)(h2buf + (size_t)(base + row) * 64 + c4);
    float* d = &h2s[row * 65 + c4];
    d[0] = v.x; d[1] = v.y; d[2] = v.z; d[3] = v.w;
  }
  const int ty = tid >> 5, tx = tid & 31;
  const float* w3p = ew3 + (size_t)e * 64000;
  const float* b3p = eb3 + (size_t)e * 1000;
  for (int nc = 0; nc < 8; nc++) {
    const int o0 = nc * 128;
    for (int i = tid; i < 2048; i += TPB) {
      const int row = i / 16, c4 = (i - row * 16) * 4;
      const int o = o0 + row;
      float4 u = (o < 1000) ? *(const float4*)(w3p + (size_t)o * 64 + c4)
                            : make_float4(0.f, 0.f, 0.f, 0.f);
      float* d = &w3s[row * 65 + c4];
      d[0] = u.x; d[1] = u.y; d[2] = u.z; d[3] = u.w;
    }
    __syncthreads();
    float acc[4][4] = {{0.f}};
    for (int k = 0; k < 64; k++) {
      float a_[4], w_[4];
#pragma unroll
      for (int i = 0; i < 4; i++) a_[i] = h2s[(ty * 4 + i) * 65 + k];
#pragma unroll
      for (int j = 0; j < 4; j++) w_[j] = w3s[(tx * 4 + j) * 65 + k];
#pragma unroll
      for (int i = 0; i < 4; i++)
#pragma unroll
        for (int j = 0; j < 4; j++) acc[i][j] = fmaf(a_[i], w_[j], acc[i][j]);
    }
#pragma unroll
    for (int j = 0; j < 4; j++) {
      const int o = o0 + tx * 4 + j;
      if (o < 1000) {
        const float bb = b3p[o];
#pragma unroll
        for (int i = 0; i < 4; i++)
          eo[(size_t)(base + ty * 4 + i) * 1000 + o] = acc[i][j] + bb;
      }
    }
    __syncthreads();
  }
}

// ---------------- K8: gate-combine + log_softmax(|.|) ----------------------
__global__ __launch_bounds__(TPB) void k_out(
    const float* __restrict__ eo, const int* __restrict__ p0,
    const int* __restrict__ p1, const float* __restrict__ wt0,
    const float* __restrict__ wt1, float* __restrict__ out)
{
  __shared__ float sv[1000];
  __shared__ float sr[8];
  const int r = blockIdx.x, tid = threadIdx.x;
  const float w0 = wt0[r], w1 = wt1[r];
  const float* a = eo + (size_t)p0[r] * 1000;
  const float* b = eo + (size_t)p1[r] * 1000;
  float lmax = -3.4e38f;
  for (int o = tid; o < 1000; o += TPB) {
    const float v = fabsf(w0 * a[o] + w1 * b[o]);
    sv[o] = v;
    lmax = fmaxf(lmax, v);
  }
#pragma unroll
  for (int off = 32; off; off >>= 1) lmax = fmaxf(lmax, __shfl_down(lmax, off));
  if ((tid & 63) == 0) sr[tid >> 6] = lmax;
  __syncthreads();
  const float mx = fmaxf(fmaxf(sr[0], sr[1]), fmaxf(sr[2], sr[3]));
  float lsum = 0.f;
  for (int o = tid; o < 1000; o += TPB) lsum += expf(sv[o] - mx);
#pragma unroll
  for (int off = 32; off; off >>= 1) lsum += __shfl_down(lsum, off);
  if ((tid & 63) == 0) sr[4 + (tid >> 6)] = lsum;
  __syncthreads();
  const float lse = logf(sr[4] + sr[5] + sr[6] + sr[7]);
  const float sub = mx + lse;
  for (int o = tid; o < 1000; o += TPB)
    out[(size_t)r * 1000 + o] = sv[o] - sub;
}

// ---------------------------------------------------------------------------
extern "C" void kernel_launch(void* const* d_in, const int* in_sizes, int n_in,
                              void* d_out, int out_size, void* d_ws, size_t ws_size,
                              hipStream_t stream)
{
  (void)in_sizes; (void)n_in; (void)out_size; (void)ws_size;
  const float* x   = (const float*)d_in[0];
  const float* c1w = (const float*)d_in[1];
  const float* c1b = (const float*)d_in[2];
  const float* bng = (const float*)d_in[3];
  const float* bnb = (const float*)d_in[4];
  const float* c2w = (const float*)d_in[5];
  const float* c2b = (const float*)d_in[6];
  const float* gw1 = (const float*)d_in[7];
  const float* gb1 = (const float*)d_in[8];
  const float* gw2 = (const float*)d_in[9];
  const float* gb2 = (const float*)d_in[10];
  const float* ew1 = (const float*)d_in[11];
  const float* eb1 = (const float*)d_in[12];
  const float* ew2 = (const float*)d_in[13];
  const float* eb2 = (const float*)d_in[14];
  const float* ew3 = (const float*)d_in[15];
  const float* eb3 = (const float*)d_in[16];

  // workspace layout (bytes)
  char* ws = (char*)d_ws;
  float* statsF = (float*)ws;                       //   0: sum10 sumsq10 scale10 shift10
  int*   hdrI   = (int*)(ws + 256);                 // 256: count8 cursor8 pcnt8 poff9
  int*   sel0   = (int*)(ws + 1024);                // 4096 ints
  int*   sel1   = (int*)(ws + 17408);
  float* wt0    = (float*)(ws + 33792);
  float* wt1    = (float*)(ws + 50176);
  int*   p0     = (int*)(ws + 66560);
  int*   p1     = (int*)(ws + 82944);
  int*   entrow = (int*)(ws + 99328);               // 8448 ints
  float* graw   = (float*)(ws + 133120);            // 4096x64
  float* h2buf  = (float*)(ws + 1181696);           // 8448x64
  float* eo     = (float*)(ws + 3344384);           // 8448x1000
  __hip_bfloat16* pool1 = (__hip_bfloat16*)(ws + 37136384);  // 4096x10x31x31 bf16
  float* feat   = (float*)(ws + 115861504);         // 4096x3920  (ends ~180 MB)

  hipMemsetAsync(ws, 0, 512, stream);                        // stats + counts
  hipMemsetAsync(graw, 0, 4096 * 64 * sizeof(float), stream);

  k_conv1  <<<4096, TPB, 0, stream>>>(x, c1w, c1b, pool1, statsF);
  k_bnfin  <<<1, 64, 0, stream>>>(bng, bnb, statsF);
  k_conv2  <<<4096, TPB, 0, stream>>>(pool1, statsF, c2w, c2b, feat);
  k_gate1  <<<dim3(64, 4), TPB, 0, stream>>>(feat, gw1, graw);
  k_gate2  <<<16, TPB, 0, stream>>>(graw, gb1, gw2, gb2, sel0, sel1, wt0, wt1, hdrI);
  k_prep   <<<1, TPB, 0, stream>>>(hdrI, entrow);
  k_scatter<<<16, TPB, 0, stream>>>(sel0, sel1, hdrI, entrow, p0, p1);
  k_fc12   <<<dim3(128, 8), TPB, 0, stream>>>(feat, ew1, eb1, ew2, eb2, hdrI, entrow, h2buf);
  k_fc3    <<<dim3(128, 8), TPB, 0, stream>>>(h2buf, ew3, eb3, hdrI, eo);
  k_out    <<<4096, TPB, 0, stream>>>(eo, p0, p1, wt0, wt1, (float*)d_out);
}

// Round 2
// 1612.313 us; speedup vs baseline: 1.4375x; 1.4375x over previous
//
#include <hip/hip_runtime.h>
#include <hip/hip_bf16.h>

// ---------------------------------------------------------------------------
// Net_83674552861196 — round 2: expert path on MFMA.
//  - k_conv2 emits feat directly as bf16 [4096][4160] (K padded 3920->4096+64,
//    pad cols zeroed) consumed by both gate and fc1.
//  - k_castw1: ew1 -> bf16 [1024][4160] (row o = e*128+h), zero-padded.
//  - k_fc1: dense MFMA bf16 GEMM C[4096][1024] = feat . W1^T, 128x128 tiles,
//    512 thr (8 waves of 32x64), 16x16x32 bf16 MFMA, bias+relu -> h1 bf16.
//  - k_fc2: dense per-expert 64-row tiles, fp32 LDS, -> h2 fp32 [4096][8*64].
//  - k_fc3: grouped (top-2 only), gathers h2 via entry list, transposed w3
//    LDS ([k][o]) so inner reads are float4 (old layout was 4/8-way conflicted).
// ---------------------------------------------------------------------------

#define TPB 256

typedef __attribute__((ext_vector_type(8))) short bf16x8;
typedef __attribute__((ext_vector_type(4))) float f32x4;

__device__ __forceinline__ float bf2f(unsigned short u) {
  return __uint_as_float(((unsigned)u) << 16);
}

// ---------------- K1: conv1 + raw-maxpool + BN statistics ------------------
__global__ __launch_bounds__(TPB) void k_conv1(
    const float* __restrict__ x, const float* __restrict__ w1c,
    const float* __restrict__ b1c, __hip_bfloat16* __restrict__ pool1,
    float* __restrict__ stats /* sum[10], sumsq[10] */)
{
  __shared__ float simg[12288];           // 3x64x64 image, 48 KB
  const int tid = threadIdx.x;
  const int n = blockIdx.x;
  {
    const float4* s = (const float4*)(x + (size_t)n * 12288);
    float4* d = (float4*)simg;
#pragma unroll
    for (int i = 0; i < 12; i++) d[tid + 256 * i] = s[tid + 256 * i];
  }
  __syncthreads();

  float ts[10], tss[10];
#pragma unroll
  for (int c = 0; c < 10; c++) { ts[c] = 0.f; tss[c] = 0.f; }

  for (int p = tid; p < 961; p += TPB) {   // pool output 31x31
    const int ph = p / 31, pw = p - 31 * ph;
    float acc[4][10];
#pragma unroll
    for (int i = 0; i < 4; i++)
#pragma unroll
      for (int c = 0; c < 10; c++) acc[i][c] = 0.f;

    for (int ic = 0; ic < 3; ic++) {
      float pat[6][6];
#pragma unroll
      for (int rr = 0; rr < 6; rr++) {
        const int r = 2 * ph - 1 + rr;
        const bool rok = (r >= 0) && (r < 64);
#pragma unroll
        for (int cc = 0; cc < 6; cc++) {
          const int cI = 2 * pw - 1 + cc;
          pat[rr][cc] = (rok && (cI >= 0) && (cI < 64))
                            ? simg[ic * 4096 + (r << 6) + cI] : 0.f;
        }
      }
      const float* wp = w1c + ic * 25;
#pragma unroll
      for (int kh = 0; kh < 5; kh++)
#pragma unroll
        for (int kw = 0; kw < 5; kw++) {
          const float p00 = pat[kh][kw],     p01 = pat[kh][kw + 1];
          const float p10 = pat[kh + 1][kw], p11 = pat[kh + 1][kw + 1];
#pragma unroll
          for (int oc = 0; oc < 10; oc++) {
            const float wv = wp[oc * 75 + kh * 5 + kw];
            acc[0][oc] = fmaf(wv, p00, acc[0][oc]);
            acc[1][oc] = fmaf(wv, p01, acc[1][oc]);
            acc[2][oc] = fmaf(wv, p10, acc[2][oc]);
            acc[3][oc] = fmaf(wv, p11, acc[3][oc]);
          }
        }
    }
#pragma unroll
    for (int oc = 0; oc < 10; oc++) {
      const float bb = b1c[oc];
      const float y0 = acc[0][oc] + bb, y1 = acc[1][oc] + bb;
      const float y2 = acc[2][oc] + bb, y3 = acc[3][oc] + bb;
      ts[oc]  += (y0 + y1) + (y2 + y3);
      tss[oc] += y0 * y0 + y1 * y1 + y2 * y2 + y3 * y3;
      const float m = fmaxf(fmaxf(y0, y1), fmaxf(y2, y3));
      pool1[((size_t)(n * 10 + oc)) * 961 + p] = __float2bfloat16(m);
    }
  }

  __shared__ float sred[20];
  if (tid < 20) sred[tid] = 0.f;
  __syncthreads();
#pragma unroll
  for (int c = 0; c < 10; c++) {
    atomicAdd(&sred[c], ts[c]);
    atomicAdd(&sred[10 + c], tss[c]);
  }
  __syncthreads();
  if (tid < 20) atomicAdd(&stats[tid], sred[tid]);
}

// ---------------- K2: finalize BN scale/shift ------------------------------
__global__ void k_bnfin(const float* __restrict__ bng,
                        const float* __restrict__ bnb,
                        float* __restrict__ stats)
{
  const int c = threadIdx.x;
  if (c < 10) {
    const float Ninv = 1.f / (4096.f * 3844.f);
    const float mean = stats[c] * Ninv;
    const float var = stats[10 + c] * Ninv - mean * mean;
    const float sc = bng[c] * rsqrtf(var + 1e-5f);
    stats[20 + c] = sc;
    stats[30 + c] = bnb[c] - mean * sc;
  }
}

// ---------------- K3: BN+relu, conv2 + pool2 -> featb (bf16, padded) -------
__global__ __launch_bounds__(TPB) void k_conv2(
    const __hip_bfloat16* __restrict__ pool1, const float* __restrict__ stats,
    const float* __restrict__ w2c, const float* __restrict__ b2c,
    __hip_bfloat16* __restrict__ featb)
{
  __shared__ float sp[10 * 1089];          // 10 x 33 x 33 zero-padded
  __shared__ float ssc[10], ssh[10];
  const int tid = threadIdx.x;
  const int n = blockIdx.x;
  if (tid < 10) { ssc[tid] = stats[20 + tid]; ssh[tid] = stats[30 + tid]; }
  for (int i = tid; i < 10890; i += TPB) sp[i] = 0.f;
  __syncthreads();
  const __hip_bfloat16* src = pool1 + (size_t)n * 9610;
  for (int i = tid; i < 9610; i += TPB) {
    const int ic = i / 961, rem = i - ic * 961;
    const int r = rem / 31, c = rem - r * 31;
    float v = __bfloat162float(src[i]);
    v = fmaxf(fmaf(v, ssc[ic], ssh[ic]), 0.f);
    sp[ic * 1089 + (r + 1) * 33 + (c + 1)] = v;
  }
  __syncthreads();

  if (tid < 196) {                         // pool2 output 14x14
    const int qh = tid / 14, qw = tid - 14 * (tid / 14);
    for (int half = 0; half < 2; half++) {
      float acc[4][10];
#pragma unroll
      for (int i = 0; i < 4; i++)
#pragma unroll
        for (int j = 0; j < 10; j++) acc[i][j] = b2c[half * 10 + j];
      for (int ic = 0; ic < 10; ic++) {
        float pat[6][6];
        const float* base = &sp[ic * 1089 + 2 * qh * 33 + 2 * qw];
#pragma unroll
        for (int rr = 0; rr < 6; rr++)
#pragma unroll
          for (int cc = 0; cc < 6; cc++) pat[rr][cc] = base[rr * 33 + cc];
        const float* wp = w2c + (half * 10) * 250 + ic * 25;
#pragma unroll
        for (int kh = 0; kh < 5; kh++)
#pragma unroll
          for (int kw = 0; kw < 5; kw++) {
            const float p00 = pat[kh][kw],     p01 = pat[kh][kw + 1];
            const float p10 = pat[kh + 1][kw], p11 = pat[kh + 1][kw + 1];
#pragma unroll
            for (int j = 0; j < 10; j++) {
              const float wv = wp[j * 250 + kh * 5 + kw];
              acc[0][j] = fmaf(wv, p00, acc[0][j]);
              acc[1][j] = fmaf(wv, p01, acc[1][j]);
              acc[2][j] = fmaf(wv, p10, acc[2][j]);
              acc[3][j] = fmaf(wv, p11, acc[3][j]);
            }
          }
      }
      __hip_bfloat16* fdst = featb + (size_t)n * 4160 + (half * 10) * 196 + tid;
#pragma unroll
      for (int j = 0; j < 10; j++) {
        const float m = fmaxf(
            fmaxf(fmaxf(acc[0][j], acc[1][j]), fmaxf(acc[2][j], acc[3][j])), 0.f);
        fdst[j * 196] = __float2bfloat16(m);
      }
    }
  }
  if (tid < 240)                            // zero K-pad cols 3920..4159
    featb[(size_t)n * 4160 + 3920 + tid] = __float2bfloat16(0.f);
}

// ---------------- K3b: cast ew1 -> bf16 [1024][4160] -----------------------
__global__ __launch_bounds__(TPB) void k_castw1(
    const float* __restrict__ ew1, ushort* __restrict__ w1b)
{
  const int o = blockIdx.x;                 // 0..1023 (= e*128 + h)
  const int tid = threadIdx.x;
  const float* srow = ew1 + (size_t)o * 3920;
  ushort* drow = w1b + (size_t)o * 4160;
  for (int i = tid; i < 1040; i += TPB) {   // 4160/4 units
    const int k4 = i * 4;
    ushort4 r;
    if (k4 < 3920) {
      const float4 v = *(const float4*)(srow + k4);
      r.x = (ushort)(__float_as_uint(v.x) >> 16);  // truncation is NOT used:
      // use RNE via intrinsic below instead
      r.x = *(ushort*)&(*(__hip_bfloat16*)&r.x);   // placeholder, overwritten
      __hip_bfloat16 b0 = __float2bfloat16(v.x);
      __hip_bfloat16 b1 = __float2bfloat16(v.y);
      __hip_bfloat16 b2 = __float2bfloat16(v.z);
      __hip_bfloat16 b3 = __float2bfloat16(v.w);
      r.x = *(ushort*)&b0; r.y = *(ushort*)&b1;
      r.z = *(ushort*)&b2; r.w = *(ushort*)&b3;
    } else {
      r.x = 0; r.y = 0; r.z = 0; r.w = 0;
    }
    *(ushort4*)(drow + k4) = r;
  }
}

// ---------------- K4a: gate fc1 partial GEMM (atomic K-split) --------------
__global__ __launch_bounds__(TPB) void k_gate1(
    const ushort* __restrict__ featb, const float* __restrict__ gw1,
    float* __restrict__ graw)
{
  __shared__ float sf[64 * 113];
  __shared__ float sw[64 * 113];
  const int tid = threadIdx.x;
  const int r0 = blockIdx.x * 64;
  const int kz = blockIdx.y;
  const int ty = tid >> 4, tx = tid & 15;
  float acc[4][4] = {{0.f}};
  for (int c = kz; c < 35; c += 4) {
    const int k0 = c * 112;
    for (int i = tid; i < 896; i += TPB) {       // feat 64 rows x 14 (bf16x8)
      const int row = i / 14, k8 = (i - row * 14) * 8;
      uint4 v = *(const uint4*)(featb + (size_t)(r0 + row) * 4160 + k0 + k8);
      const ushort* pv = (const ushort*)&v;
      float* d = &sf[row * 113 + k8];
#pragma unroll
      for (int t = 0; t < 8; t++) d[t] = bf2f(pv[t]);
    }
    for (int i = tid; i < 1792; i += TPB) {      // gw1 fp32 64 x 112
      const int row = i / 28, c4 = (i - row * 28) * 4;
      float4 u = *(const float4*)(gw1 + (size_t)row * 3920 + k0 + c4);
      float* e = &sw[row * 113 + c4];
      e[0] = u.x; e[1] = u.y; e[2] = u.z; e[3] = u.w;
    }
    __syncthreads();
    for (int k = 0; k < 112; k++) {
      float a_[4], w_[4];
#pragma unroll
      for (int i = 0; i < 4; i++) a_[i] = sf[(ty * 4 + i) * 113 + k];
#pragma unroll
      for (int j = 0; j < 4; j++) w_[j] = sw[(tx * 4 + j) * 113 + k];
#pragma unroll
      for (int i = 0; i < 4; i++)
#pragma unroll
        for (int j = 0; j < 4; j++) acc[i][j] = fmaf(a_[i], w_[j], acc[i][j]);
    }
    __syncthreads();
  }
#pragma unroll
  for (int i = 0; i < 4; i++)
#pragma unroll
    for (int j = 0; j < 4; j++)
      atomicAdd(&graw[(size_t)(r0 + ty * 4 + i) * 64 + tx * 4 + j], acc[i][j]);
}

// ---------------- K4b: gate logits + top2 softmax + expert counts ----------
__global__ __launch_bounds__(TPB) void k_gate2(
    const float* __restrict__ graw, const float* __restrict__ gb1,
    const float* __restrict__ gw2, const float* __restrict__ gb2,
    int* __restrict__ sel0, int* __restrict__ sel1,
    float* __restrict__ wt0, float* __restrict__ wt1, int* __restrict__ counts)
{
  __shared__ float sw2[512], sb1[64], sb2[8];
  const int tid = threadIdx.x;
  for (int i = tid; i < 512; i += TPB) sw2[i] = gw2[i];
  if (tid < 64) sb1[tid] = gb1[tid];
  if (tid < 8) sb2[tid] = gb2[tid];
  __syncthreads();
  const int r = blockIdx.x * TPB + tid;
  float l[8];
#pragma unroll
  for (int c = 0; c < 8; c++) l[c] = sb2[c];
  const float* gr = graw + (size_t)r * 64;
  for (int k = 0; k < 64; k++) {
    const float hv = fmaxf(gr[k] + sb1[k], 0.f);
#pragma unroll
    for (int c = 0; c < 8; c++) l[c] = fmaf(hv, sw2[c * 64 + k], l[c]);
  }
  float v0 = -1e30f, v1 = -1e30f; int i0 = 0, i1 = 0;
#pragma unroll
  for (int c = 0; c < 8; c++) {
    const float lv = l[c];
    if (lv > v0) { v1 = v0; i1 = i0; v0 = lv; i0 = c; }
    else if (lv > v1) { v1 = lv; i1 = c; }
  }
  const float e1 = expf(v1 - v0);
  const float inv = 1.f / (1.f + e1);
  sel0[r] = i0; sel1[r] = i1; wt0[r] = inv; wt1[r] = e1 * inv;
  atomicAdd(&counts[i0], 1);
  atomicAdd(&counts[i1], 1);
}

// ---------------- K5: padded offsets + entry-list init ---------------------
__global__ void k_prep(int* __restrict__ hdrI, int* __restrict__ entrow)
{
  const int tid = threadIdx.x;
  if (tid == 0) {
    int run = 0;
    for (int e = 0; e < 8; e++) {
      const int c = hdrI[e];
      const int pc = (c + 31) & ~31;
      hdrI[16 + e] = pc;
      hdrI[24 + e] = run;
      run += pc;
    }
    hdrI[32] = run;
  }
  if (tid >= 8 && tid < 16) hdrI[tid] = 0;
  for (int i = tid; i < 8448; i += TPB) entrow[i] = -1;
}

// ---------------- K5b: scatter rows to expert entry lists ------------------
__global__ void k_scatter(const int* __restrict__ sel0, const int* __restrict__ sel1,
                          int* __restrict__ hdrI, int* __restrict__ entrow,
                          int* __restrict__ p0, int* __restrict__ p1)
{
  const int r = blockIdx.x * TPB + threadIdx.x;
  const int e0 = sel0[r];
  int pos = atomicAdd(&hdrI[8 + e0], 1) + hdrI[24 + e0];
  entrow[pos] = r; p0[r] = pos;
  const int e1 = sel1[r];
  pos = atomicAdd(&hdrI[8 + e1], 1) + hdrI[24 + e1];
  entrow[pos] = r; p1[r] = pos;
}

// ---------------- K6: dense MFMA fc1 -> h1 bf16 [4096][1024] ---------------
// C[m][n] = sum_k featb[m][k] * w1b[n][k]; 128x128 tile per block,
// 8 waves of 32(rows)x64(cols), 16x16x32 bf16 MFMA, BK=64.
__global__ __launch_bounds__(512) void k_fc1(
    const ushort* __restrict__ featb, const ushort* __restrict__ w1b,
    const float* __restrict__ eb1, __hip_bfloat16* __restrict__ h1b)
{
  __shared__ ushort As[128 * 72];   // 18432 B, stride 72 (144 B, 16B-aligned)
  __shared__ ushort Bs[128 * 72];
  const int tid = threadIdx.x;
  const int r0 = blockIdx.x * 128;
  const int c0 = blockIdx.y * 128;
  const int w = tid >> 6, lane = tid & 63;
  const int wr = (w >> 1) * 32, wc = (w & 1) * 64;
  const int m = lane & 15, q = lane >> 4;
  f32x4 acc[2][4];
#pragma unroll
  for (int i = 0; i < 2; i++)
#pragma unroll
    for (int j = 0; j < 4; j++) acc[i][j] = 0.f;

  for (int kc = 0; kc < 4096; kc += 64) {
#pragma unroll
    for (int i = 0; i < 2; i++) {           // stage A/B 128x64 bf16 each
      const int u = tid + 512 * i;          // 0..1023
      const int row = u >> 3, k8 = (u & 7) * 8;
      *(uint4*)(&As[row * 72 + k8]) =
          *(const uint4*)(featb + (size_t)(r0 + row) * 4160 + kc + k8);
      *(uint4*)(&Bs[row * 72 + k8]) =
          *(const uint4*)(w1b + (size_t)(c0 + row) * 4160 + kc + k8);
    }
    __syncthreads();
#pragma unroll
    for (int kk = 0; kk < 64; kk += 32) {
      bf16x8 af[2], bf[4];
#pragma unroll
      for (int t = 0; t < 2; t++)
        af[t] = *(const bf16x8*)(&As[(wr + t * 16 + m) * 72 + kk + q * 8]);
#pragma unroll
      for (int t = 0; t < 4; t++)
        bf[t] = *(const bf16x8*)(&Bs[(wc + t * 16 + m) * 72 + kk + q * 8]);
#pragma unroll
      for (int ti = 0; ti < 2; ti++)
#pragma unroll
        for (int tj = 0; tj < 4; tj++)
          acc[ti][tj] = __builtin_amdgcn_mfma_f32_16x16x32_bf16(
              af[ti], bf[tj], acc[ti][tj], 0, 0, 0);
    }
    __syncthreads();
  }
  // epilogue: bias + relu, store bf16. C layout: col=lane&15, row=q*4+reg.
#pragma unroll
  for (int tj = 0; tj < 4; tj++) {
    const int c = c0 + wc + tj * 16 + m;
    const float bb = eb1[c];
#pragma unroll
    for (int ti = 0; ti < 2; ti++) {
      const int rbase = r0 + wr + ti * 16 + q * 4;
#pragma unroll
      for (int i = 0; i < 4; i++) {
        const float v = fmaxf(acc[ti][tj][i] + bb, 0.f);
        h1b[(size_t)(rbase + i) * 1024 + c] = __float2bfloat16(v);
      }
    }
  }
}

// ---------------- K7: dense fc2 -> h2 fp32 [4096][512] ---------------------
__global__ __launch_bounds__(TPB) void k_fc2(
    const __hip_bfloat16* __restrict__ h1b, const float* __restrict__ ew2,
    const float* __restrict__ eb2, float* __restrict__ h2)
{
  __shared__ float h1s[64 * 132];          // 33792 B fp32
  __shared__ ushort w2s[128 * 72];         // 18432 B bf16, [k][n+pad]
  const int tid = threadIdx.x;
  const int r0 = blockIdx.x * 64;
  const int e = blockIdx.y;
  const ushort* hp = (const ushort*)h1b;
  // stage h1 tile (cvt bf16->fp32)
#pragma unroll
  for (int i = 0; i < 4; i++) {
    const int u = tid + 256 * i;            // 64 rows x 16 (bf16x8 units)
    const int row = u >> 4, k8 = (u & 15) * 8;
    uint4 v = *(const uint4*)(hp + (size_t)(r0 + row) * 1024 + e * 128 + k8);
    const ushort* pv = (const ushort*)&v;
    float* d = &h1s[row * 132 + k8];
#pragma unroll
    for (int t = 0; t < 8; t++) d[t] = bf2f(pv[t]);
  }
  // stage w2 transposed [k][n] as bf16
#pragma unroll
  for (int i = 0; i < 8; i++) {
    const int u = tid + 256 * i;            // 64 n x 32 k4-units
    const int n = u >> 5, k4 = (u & 31) * 4;
    const float4 v = *(const float4*)(ew2 + (size_t)e * 8192 + n * 128 + k4);
    __hip_bfloat16 b0 = __float2bfloat16(v.x), b1 = __float2bfloat16(v.y);
    __hip_bfloat16 b2 = __float2bfloat16(v.z), b3 = __float2bfloat16(v.w);
    w2s[(k4 + 0) * 72 + n] = *(ushort*)&b0;
    w2s[(k4 + 1) * 72 + n] = *(ushort*)&b1;
    w2s[(k4 + 2) * 72 + n] = *(ushort*)&b2;
    w2s[(k4 + 3) * 72 + n] = *(ushort*)&b3;
  }
  __syncthreads();
  const int ty = tid >> 4, tx = tid & 15;   // rows ty*4+i (64), n = tx*4+j (64)
  float acc[4][4] = {{0.f}};
  for (int k4 = 0; k4 < 32; k4++) {
    f32x4 a4[4];
#pragma unroll
    for (int i = 0; i < 4; i++)
      a4[i] = *(const f32x4*)(&h1s[(ty * 4 + i) * 132 + k4 * 4]);
#pragma unroll
    for (int kk = 0; kk < 4; kk++) {
      const ushort4 wu = *(const ushort4*)(&w2s[(k4 * 4 + kk) * 72 + tx * 4]);
      const float w0 = bf2f(wu.x), w1 = bf2f(wu.y);
      const float w2_ = bf2f(wu.z), w3 = bf2f(wu.w);
#pragma unroll
      for (int i = 0; i < 4; i++) {
        acc[i][0] = fmaf(a4[i][kk], w0, acc[i][0]);
        acc[i][1] = fmaf(a4[i][kk], w1, acc[i][1]);
        acc[i][2] = fmaf(a4[i][kk], w2_, acc[i][2]);
        acc[i][3] = fmaf(a4[i][kk], w3, acc[i][3]);
      }
    }
  }
  const f32x4 bb = *(const f32x4*)(eb2 + e * 64 + tx * 4);
#pragma unroll
  for (int i = 0; i < 4; i++) {
    f32x4 r;
#pragma unroll
    for (int j = 0; j < 4; j++) r[j] = fmaxf(acc[i][j] + bb[j], 0.f);
    *(f32x4*)(h2 + (size_t)(r0 + ty * 4 + i) * 512 + e * 64 + tx * 4) = r;
  }
}

// ---------------- K8: grouped fc3 -> eo [pos][1000] ------------------------
__global__ __launch_bounds__(TPB) void k_fc3(
    const float* __restrict__ h2, const float* __restrict__ ew3,
    const float* __restrict__ eb3, const int* __restrict__ hdrI,
    const int* __restrict__ entrow, float* __restrict__ eo)
{
  __shared__ float h2s[32 * 68];            // 8704 B
  __shared__ float w3s[64 * 132];           // 33792 B, transposed [k][o+pad]
  const int e = blockIdx.y;
  const int pcnt = hdrI[16 + e];
  if ((int)blockIdx.x * 32 >= pcnt) return;
  const int base = hdrI[24 + e] + blockIdx.x * 32;
  const int tid = threadIdx.x;
  for (int i = tid; i < 512; i += TPB) {    // gather h2 rows (32 x 64)
    const int row = i >> 4, k4 = (i & 15) * 4;
    const int rr = entrow[base + row];
    f32x4 v = 0.f;
    if (rr >= 0) v = *(const f32x4*)(h2 + (size_t)rr * 512 + e * 64 + k4);
    *(f32x4*)(&h2s[row * 68 + k4]) = v;
  }
  const int ty = tid >> 5, tx = tid & 31;   // rows ty*4+i (32), cols tx*4+j (128)
  const float* w3p = ew3 + (size_t)e * 64000;
  const float* b3p = eb3 + (size_t)e * 1000;
  for (int nc = 0; nc < 8; nc++) {
    const int o0 = nc * 128;
    for (int i = tid; i < 2048; i += TPB) { // stage w3 chunk transposed
      const int oo = i >> 4, k4 = (i & 15) * 4;
      const int o = o0 + oo;
      f32x4 u = 0.f;
      if (o < 1000) u = *(const f32x4*)(w3p + (size_t)o * 64 + k4);
      w3s[(k4 + 0) * 132 + oo] = u[0];
      w3s[(k4 + 1) * 132 + oo] = u[1];
      w3s[(k4 + 2) * 132 + oo] = u[2];
      w3s[(k4 + 3) * 132 + oo] = u[3];
    }
    __syncthreads();
    float acc[4][4] = {{0.f}};
    for (int k4 = 0; k4 < 16; k4++) {
      f32x4 a4[4], w4[4];
#pragma unroll
      for (int i = 0; i < 4; i++)
        a4[i] = *(const f32x4*)(&h2s[(ty * 4 + i) * 68 + k4 * 4]);
#pragma unroll
      for (int kk = 0; kk < 4; kk++)
        w4[kk] = *(const f32x4*)(&w3s[(k4 * 4 + kk) * 132 + tx * 4]);
#pragma unroll
      for (int kk = 0; kk < 4; kk++)
#pragma unroll
        for (int i = 0; i < 4; i++)
#pragma unroll
          for (int j = 0; j < 4; j++)
            acc[i][j] = fmaf(a4[i][kk], w4[kk][j], acc[i][j]);
    }
    const int o = o0 + tx * 4;
    if (o + 3 < 1000) {
      const f32x4 bb = *(const f32x4*)(b3p + o);
#pragma unroll
      for (int i = 0; i < 4; i++) {
        f32x4 r;
#pragma unroll
        for (int j = 0; j < 4; j++) r[j] = acc[i][j] + bb[j];
        *(f32x4*)(eo + (size_t)(base + ty * 4 + i) * 1000 + o) = r;
      }
    }
    __syncthreads();
  }
}

// ---------------- K9: gate-combine + log_softmax(|.|) ----------------------
__global__ __launch_bounds__(TPB) void k_out(
    const float* __restrict__ eo, const int* __restrict__ p0,
    const int* __restrict__ p1, const float* __restrict__ wt0,
    const float* __restrict__ wt1, float* __restrict__ out)
{
  __shared__ float sv[1000];
  __shared__ float sr[8];
  const int r = blockIdx.x, tid = threadIdx.x;
  const float w0 = wt0[r], w1 = wt1[r];
  const float* a = eo + (size_t)p0[r] * 1000;
  const float* b = eo + (size_t)p1[r] * 1000;
  float lmax = -3.4e38f;
  for (int o = tid; o < 1000; o += TPB) {
    const float v = fabsf(w0 * a[o] + w1 * b[o]);
    sv[o] = v;
    lmax = fmaxf(lmax, v);
  }
#pragma unroll
  for (int off = 32; off; off >>= 1) lmax = fmaxf(lmax, __shfl_down(lmax, off));
  if ((tid & 63) == 0) sr[tid >> 6] = lmax;
  __syncthreads();
  const float mx = fmaxf(fmaxf(sr[0], sr[1]), fmaxf(sr[2], sr[3]));
  float lsum = 0.f;
  for (int o = tid; o < 1000; o += TPB) lsum += expf(sv[o] - mx);
#pragma unroll
  for (int off = 32; off; off >>= 1) lsum += __shfl_down(lsum, off);
  if ((tid & 63) == 0) sr[4 + (tid >> 6)] = lsum;
  __syncthreads();
  const float lse = logf(sr[4] + sr[5] + sr[6] + sr[7]);
  const float sub = mx + lse;
  for (int o = tid; o < 1000; o += TPB)
    out[(size_t)r * 1000 + o] = sv[o] - sub;
}

// ---------------------------------------------------------------------------
extern "C" void kernel_launch(void* const* d_in, const int* in_sizes, int n_in,
                              void* d_out, int out_size, void* d_ws, size_t ws_size,
                              hipStream_t stream)
{
  (void)in_sizes; (void)n_in; (void)out_size; (void)ws_size;
  const float* x   = (const float*)d_in[0];
  const float* c1w = (const float*)d_in[1];
  const float* c1b = (const float*)d_in[2];
  const float* bng = (const float*)d_in[3];
  const float* bnb = (const float*)d_in[4];
  const float* c2w = (const float*)d_in[5];
  const float* c2b = (const float*)d_in[6];
  const float* gw1 = (const float*)d_in[7];
  const float* gb1 = (const float*)d_in[8];
  const float* gw2 = (const float*)d_in[9];
  const float* gb2 = (const float*)d_in[10];
  const float* ew1 = (const float*)d_in[11];
  const float* eb1 = (const float*)d_in[12];
  const float* ew2 = (const float*)d_in[13];
  const float* eb2 = (const float*)d_in[14];
  const float* ew3 = (const float*)d_in[15];
  const float* eb3 = (const float*)d_in[16];

  char* ws = (char*)d_ws;
  float* statsF = (float*)ws;                        //   0
  int*   hdrI   = (int*)(ws + 256);
  int*   sel0   = (int*)(ws + 1024);
  int*   sel1   = (int*)(ws + 17408);
  float* wt0    = (float*)(ws + 33792);
  float* wt1    = (float*)(ws + 50176);
  int*   p0     = (int*)(ws + 66560);
  int*   p1     = (int*)(ws + 82944);
  int*   entrow = (int*)(ws + 99328);                // 8448 ints
  float* graw   = (float*)(ws + 133120);             // 4096x64
  float* eo     = (float*)(ws + 1181696);            // 8448x1000
  __hip_bfloat16* h1b = (__hip_bfloat16*)(ws + 34973696);   // 4096x1024 bf16
  float* h2     = (float*)(ws + 43362304);           // 4096x512 fp32
  __hip_bfloat16* pool1 = (__hip_bfloat16*)(ws + 51750912); // 4096x9610 bf16
  __hip_bfloat16* featb = (__hip_bfloat16*)(ws + 130476032);// 4096x4160 bf16
  ushort* w1b   = (ushort*)(ws + 164554752);         // 1024x4160 bf16 -> ends ~173MB

  hipMemsetAsync(ws, 0, 512, stream);                // stats + hdr counts
  hipMemsetAsync(graw, 0, 4096 * 64 * sizeof(float), stream);

  k_castw1 <<<1024, TPB, 0, stream>>>(ew1, w1b);
  k_conv1  <<<4096, TPB, 0, stream>>>(x, c1w, c1b, pool1, statsF);
  k_bnfin  <<<1, 64, 0, stream>>>(bng, bnb, statsF);
  k_conv2  <<<4096, TPB, 0, stream>>>(pool1, statsF, c2w, c2b, featb);
  k_gate1  <<<dim3(64, 4), TPB, 0, stream>>>((const ushort*)featb, gw1, graw);
  k_gate2  <<<16, TPB, 0, stream>>>(graw, gb1, gw2, gb2, sel0, sel1, wt0, wt1, hdrI);
  k_prep   <<<1, TPB, 0, stream>>>(hdrI, entrow);
  k_scatter<<<16, TPB, 0, stream>>>(sel0, sel1, hdrI, entrow, p0, p1);
  k_fc1    <<<dim3(32, 8), 512, 0, stream>>>((const ushort*)featb, w1b, eb1, h1b);
  k_fc2    <<<dim3(64, 8), TPB, 0, stream>>>(h1b, ew2, eb2, h2);
  k_fc3    <<<dim3(128, 8), TPB, 0, stream>>>(h2, ew3, eb3, hdrI, entrow, eo);
  k_out    <<<4096, TPB, 0, stream>>>(eo, p0, p1, wt0, wt1, (float*)d_out);
}

// Round 3
// 1460.271 us; speedup vs baseline: 1.5871x; 1.1041x over previous
//
#include <hip/hip_runtime.h>
#include <hip/hip_bf16.h>

// ---------------------------------------------------------------------------
// Net_83674552861196 — round 3: conv1 on MFMA (rolling row-im2col).
//  - k_conv1: per image, image staged bf16 zero-padded in LDS; K=(kh,ic,kw)
//    ordered so each conv row reuses prev row's im2col shifted by one 15-wide
//    slice. 8 circular row-slices + 1 zero slice in LDS; weights in registers
//    (3 B-frags); 4 waves x one 16-col m-tile; 3 MFMA/row; epilogue does
//    bias + masked BN stats + in-register 2x2 raw-max pool (pool commutes
//    with BN+relu since bn_g=1>0). pool1 layout now [n][ph][pw][oc].
//  - k_conv2: split into 2 blocks/image (oc halves), new pool1 decode.
//  - rest identical to round 2.
// ---------------------------------------------------------------------------

#define TPB 256

typedef __attribute__((ext_vector_type(8))) short bf16x8;
typedef __attribute__((ext_vector_type(4))) float f32x4;

__device__ __forceinline__ float bf2f(unsigned short u) {
  return __uint_as_float(((unsigned)u) << 16);
}
__device__ __forceinline__ ushort f2b(float f) {
  __hip_bfloat16 h = __float2bfloat16(f);
  return *(ushort*)&h;
}

// ---------------- K1: conv1 (MFMA) + raw-maxpool + BN statistics -----------
// img_pad[ic][t][u] = x[ic][t-1][u-1] (zero border), t in [0,66), u in [0,68).
// out(r,c) = b[oc] + sum_{kh,ic,kw} w * img_pad[ic][r+kh][c+kw]
//          = sum_k A[c][k].B[oc][k],  k=(kh, k15=ic*5+kw) -> 5 slices of 15.
// Slice S_t[c][k15] = img_pad[ic][t][c+kw]; row r uses slices t=r..r+4.
__global__ __launch_bounds__(TPB) void k_conv1(
    const float* __restrict__ x, const float* __restrict__ w1c,
    const float* __restrict__ b1c, __hip_bfloat16* __restrict__ pool1,
    float* __restrict__ stats)
{
  __shared__ ushort img[3 * 66 * 68];   // 26928 B
  __shared__ ushort slc[9 * 64 * 18];   // 20736 B; slot 8 = permanent zeros
  __shared__ float sred[20];
  const int tid = threadIdx.x;
  const int lane = tid & 63;
  const int w = tid >> 6;
  const int n = blockIdx.x;
  const int oc = lane & 15;             // also the m index within a 16-tile
  const int q = lane >> 4;

  // phase 0: zero LDS
  {
    uint* p = (uint*)img;
    for (int i = tid; i < 6732; i += TPB) p[i] = 0;
    uint* z = (uint*)slc;
    for (int i = tid; i < 5184; i += TPB) z[i] = 0;
    if (tid < 20) sred[tid] = 0.f;
  }
  __syncthreads();

  // phase 1: stage image bf16 into padded LDS
  {
    const float* xp = x + (size_t)n * 12288;
#pragma unroll
    for (int it = 0; it < 12; it++) {
      const int e = 4 * (tid + 256 * it);
      const float4 v = *(const float4*)(xp + e);
      const int ic = e >> 12, rem = e & 4095, row = rem >> 6, col = rem & 63;
      ushort* d = &img[ic * 4488 + (row + 1) * 68 + (col + 1)];
      d[0] = f2b(v.x); d[1] = f2b(v.y); d[2] = f2b(v.z); d[3] = f2b(v.w);
    }
  }

  // B-fragments (weights) + bias, built once per wave
  bf16x8 bfrag[3];
#pragma unroll
  for (int ch = 0; ch < 3; ch++) {
    union { ushort s[8]; bf16x8 v; } bu;
#pragma unroll
    for (int j = 0; j < 8; j++) {
      const int k15 = (q & 1) * 8 + j;
      const int kh = 2 * ch + (q >> 1);
      float wv = 0.f;
      if (oc < 10 && k15 < 15 && kh < 5) {
        const int ic = (k15 >= 10) ? 2 : ((k15 >= 5) ? 1 : 0);
        const int kw = k15 - ic * 5;
        wv = w1c[oc * 75 + ic * 25 + kh * 5 + kw];
      }
      bu.s[j] = f2b(wv);
    }
    bfrag[ch] = bu.v;
  }
  const float bias = (oc < 10) ? b1c[oc] : 0.f;

  // per-lane build assignments: wave w handles k15 = w, w+4, w+8, w+12 (<15)
  int bsrc[4], bdst[4], bcnt = 0;
#pragma unroll
  for (int j = 0; j < 4; j++) {
    const int k15 = w + 4 * j;
    if (k15 < 15) {
      const int ic = (k15 >= 10) ? 2 : ((k15 >= 5) ? 1 : 0);
      const int kw = k15 - ic * 5;
      bsrc[bcnt] = ic * 4488 + kw + lane;   // + t*68 at use
      bdst[bcnt] = lane * 18 + k15;
      bcnt++;
    }
  }

  __syncthreads();                       // img staged before slice builds

  // pre-build slices t = 0..3
  for (int t = 0; t < 4; t++) {
    ushort* sb = &slc[(t & 7) * 1152];
    const int tof = t * 68;
    for (int j = 0; j < bcnt; j++) sb[bdst[j]] = img[bsrc[j] + tof];
  }

  // per-lane constants for the main loop
  const int c0 = w * 16;                 // wave's m-tile col base
  const int fofs = (c0 + oc) * 18 + (q & 1) * 8;  // elem offset within a slot
  const bool qlo = (q < 2);
  float vm[4];
#pragma unroll
  for (int i = 0; i < 4; i++)
    vm[i] = ((c0 + q * 4 + i) < 62) ? 1.f : 0.f;

  float ts = 0.f, tss = 0.f;
  float pp0 = 0.f, pp1 = 0.f;

  for (int r = 0; r < 62; r++) {
    {  // build slice t = r+4 (slot (r+4)&7 is disjoint from live r..r+4-1 readers)
      const int t = r + 4;
      ushort* sb = &slc[(t & 7) * 1152];
      const int tof = t * 68;
      for (int j = 0; j < bcnt; j++) sb[bdst[j]] = img[bsrc[j] + tof];
    }
    __syncthreads();

    f32x4 acc = {0.f, 0.f, 0.f, 0.f};
#pragma unroll
    for (int ch = 0; ch < 3; ch++) {
      const int sa = (r + 2 * ch) & 7;
      const int sb2 = (ch == 2) ? 8 : ((r + 2 * ch + 1) & 7);
      const ushort* base = &slc[(qlo ? sa : sb2) * 1152 + fofs];
      union { uint u[4]; bf16x8 v; } au;
      au.u[0] = *(const uint*)(base + 0);
      au.u[1] = *(const uint*)(base + 2);
      au.u[2] = *(const uint*)(base + 4);
      au.u[3] = *(const uint*)(base + 6);
      acc = __builtin_amdgcn_mfma_f32_16x16x32_bf16(au.v, bfrag[ch], acc, 0, 0, 0);
    }

    // epilogue: bias, masked BN stats, 2x2 raw-max pool
    const float y0 = acc[0] + bias, y1 = acc[1] + bias;
    const float y2 = acc[2] + bias, y3 = acc[3] + bias;
    float t0 = y0 * vm[0]; ts += t0; tss = fmaf(t0, y0, tss);
    float t1 = y1 * vm[1]; ts += t1; tss = fmaf(t1, y1, tss);
    float t2 = y2 * vm[2]; ts += t2; tss = fmaf(t2, y2, tss);
    float t3 = y3 * vm[3]; ts += t3; tss = fmaf(t3, y3, tss);
    const float p0v = fmaxf(y0, y1), p1v = fmaxf(y2, y3);
    if ((r & 1) == 0) {
      pp0 = p0v; pp1 = p1v;
    } else if (oc < 10) {
      const int ph = r >> 1;
      const int pwb = (c0 >> 1) + q * 2;
      __hip_bfloat16* dst = pool1 + (size_t)n * 9610 + (size_t)(ph * 31) * 10 + oc;
      const float q0 = fmaxf(pp0, p0v), q1 = fmaxf(pp1, p1v);
      dst[pwb * 10] = __float2bfloat16(q0);            // pwb <= 30 always
      if (pwb + 1 < 31) dst[(pwb + 1) * 10] = __float2bfloat16(q1);
    }
  }

  // BN stats reduction
  if (oc < 10) {
    atomicAdd(&sred[oc], ts);
    atomicAdd(&sred[10 + oc], tss);
  }
  __syncthreads();
  if (tid < 20) atomicAdd(&stats[tid], sred[tid]);
}

// ---------------- K2: finalize BN scale/shift ------------------------------
__global__ void k_bnfin(const float* __restrict__ bng,
                        const float* __restrict__ bnb,
                        float* __restrict__ stats)
{
  const int c = threadIdx.x;
  if (c < 10) {
    const float Ninv = 1.f / (4096.f * 3844.f);
    const float mean = stats[c] * Ninv;
    const float var = stats[10 + c] * Ninv - mean * mean;
    const float sc = bng[c] * rsqrtf(var + 1e-5f);
    stats[20 + c] = sc;
    stats[30 + c] = bnb[c] - mean * sc;
  }
}

// ---------------- K3: BN+relu, conv2 + pool2 -> featb (bf16, padded) -------
// grid (4096, 2): blockIdx.y = oc-half. pool1 layout [n][ph][pw][oc].
__global__ __launch_bounds__(TPB) void k_conv2(
    const __hip_bfloat16* __restrict__ pool1, const float* __restrict__ stats,
    const float* __restrict__ w2c, const float* __restrict__ b2c,
    __hip_bfloat16* __restrict__ featb)
{
  __shared__ float sp[10 * 1089];          // 10 x 33 x 33 zero-padded
  __shared__ float ssc[10], ssh[10];
  const int tid = threadIdx.x;
  const int n = blockIdx.x;
  const int half = blockIdx.y;
  if (tid < 10) { ssc[tid] = stats[20 + tid]; ssh[tid] = stats[30 + tid]; }
  for (int i = tid; i < 10890; i += TPB) sp[i] = 0.f;
  __syncthreads();
  const __hip_bfloat16* src = pool1 + (size_t)n * 9610;
  for (int i = tid; i < 9610; i += TPB) {
    const int p = i / 10, ic = i - p * 10;
    const int r = p / 31, c = p - r * 31;
    float v = __bfloat162float(src[i]);
    v = fmaxf(fmaf(v, ssc[ic], ssh[ic]), 0.f);
    sp[ic * 1089 + (r + 1) * 33 + (c + 1)] = v;
  }
  __syncthreads();

  if (tid < 196) {                         // pool2 output 14x14
    const int qh = tid / 14, qw = tid - 14 * (tid / 14);
    float acc[4][10];
#pragma unroll
    for (int i = 0; i < 4; i++)
#pragma unroll
      for (int j = 0; j < 10; j++) acc[i][j] = b2c[half * 10 + j];
    for (int ic = 0; ic < 10; ic++) {
      float pat[6][6];
      const float* base = &sp[ic * 1089 + 2 * qh * 33 + 2 * qw];
#pragma unroll
      for (int rr = 0; rr < 6; rr++)
#pragma unroll
        for (int cc = 0; cc < 6; cc++) pat[rr][cc] = base[rr * 33 + cc];
      const float* wp = w2c + (half * 10) * 250 + ic * 25;
#pragma unroll
      for (int kh = 0; kh < 5; kh++)
#pragma unroll
        for (int kw = 0; kw < 5; kw++) {
          const float p00 = pat[kh][kw],     p01 = pat[kh][kw + 1];
          const float p10 = pat[kh + 1][kw], p11 = pat[kh + 1][kw + 1];
#pragma unroll
          for (int j = 0; j < 10; j++) {
            const float wv = wp[j * 250 + kh * 5 + kw];
            acc[0][j] = fmaf(wv, p00, acc[0][j]);
            acc[1][j] = fmaf(wv, p01, acc[1][j]);
            acc[2][j] = fmaf(wv, p10, acc[2][j]);
            acc[3][j] = fmaf(wv, p11, acc[3][j]);
          }
        }
    }
    __hip_bfloat16* fdst = featb + (size_t)n * 4160 + (half * 10) * 196 + tid;
#pragma unroll
    for (int j = 0; j < 10; j++) {
      const float m = fmaxf(
          fmaxf(fmaxf(acc[0][j], acc[1][j]), fmaxf(acc[2][j], acc[3][j])), 0.f);
      fdst[j * 196] = __float2bfloat16(m);
    }
  }
  if (half == 0 && tid < 240)              // zero K-pad cols 3920..4159
    featb[(size_t)n * 4160 + 3920 + tid] = __float2bfloat16(0.f);
}

// ---------------- K3b: cast ew1 -> bf16 [1024][4160] -----------------------
__global__ __launch_bounds__(TPB) void k_castw1(
    const float* __restrict__ ew1, ushort* __restrict__ w1b)
{
  const int o = blockIdx.x;                 // 0..1023 (= e*128 + h)
  const int tid = threadIdx.x;
  const float* srow = ew1 + (size_t)o * 3920;
  ushort* drow = w1b + (size_t)o * 4160;
  for (int i = tid; i < 1040; i += TPB) {
    const int k4 = i * 4;
    ushort4 r;
    if (k4 < 3920) {
      const float4 v = *(const float4*)(srow + k4);
      r.x = f2b(v.x); r.y = f2b(v.y); r.z = f2b(v.z); r.w = f2b(v.w);
    } else {
      r.x = 0; r.y = 0; r.z = 0; r.w = 0;
    }
    *(ushort4*)(drow + k4) = r;
  }
}

// ---------------- K4a: gate fc1 partial GEMM (atomic K-split) --------------
__global__ __launch_bounds__(TPB) void k_gate1(
    const ushort* __restrict__ featb, const float* __restrict__ gw1,
    float* __restrict__ graw)
{
  __shared__ float sf[64 * 113];
  __shared__ float sw[64 * 113];
  const int tid = threadIdx.x;
  const int r0 = blockIdx.x * 64;
  const int kz = blockIdx.y;
  const int ty = tid >> 4, tx = tid & 15;
  float acc[4][4] = {{0.f}};
  for (int c = kz; c < 35; c += 4) {
    const int k0 = c * 112;
    for (int i = tid; i < 896; i += TPB) {       // feat 64 rows x 14 (bf16x8)
      const int row = i / 14, k8 = (i - row * 14) * 8;
      uint4 v = *(const uint4*)(featb + (size_t)(r0 + row) * 4160 + k0 + k8);
      const ushort* pv = (const ushort*)&v;
      float* d = &sf[row * 113 + k8];
#pragma unroll
      for (int t = 0; t < 8; t++) d[t] = bf2f(pv[t]);
    }
    for (int i = tid; i < 1792; i += TPB) {      // gw1 fp32 64 x 112
      const int row = i / 28, c4 = (i - row * 28) * 4;
      float4 u = *(const float4*)(gw1 + (size_t)row * 3920 + k0 + c4);
      float* e = &sw[row * 113 + c4];
      e[0] = u.x; e[1] = u.y; e[2] = u.z; e[3] = u.w;
    }
    __syncthreads();
    for (int k = 0; k < 112; k++) {
      float a_[4], w_[4];
#pragma unroll
      for (int i = 0; i < 4; i++) a_[i] = sf[(ty * 4 + i) * 113 + k];
#pragma unroll
      for (int j = 0; j < 4; j++) w_[j] = sw[(tx * 4 + j) * 113 + k];
#pragma unroll
      for (int i = 0; i < 4; i++)
#pragma unroll
        for (int j = 0; j < 4; j++) acc[i][j] = fmaf(a_[i], w_[j], acc[i][j]);
    }
    __syncthreads();
  }
#pragma unroll
  for (int i = 0; i < 4; i++)
#pragma unroll
    for (int j = 0; j < 4; j++)
      atomicAdd(&graw[(size_t)(r0 + ty * 4 + i) * 64 + tx * 4 + j], acc[i][j]);
}

// ---------------- K4b: gate logits + top2 softmax + expert counts ----------
__global__ __launch_bounds__(TPB) void k_gate2(
    const float* __restrict__ graw, const float* __restrict__ gb1,
    const float* __restrict__ gw2, const float* __restrict__ gb2,
    int* __restrict__ sel0, int* __restrict__ sel1,
    float* __restrict__ wt0, float* __restrict__ wt1, int* __restrict__ counts)
{
  __shared__ float sw2[512], sb1[64], sb2[8];
  const int tid = threadIdx.x;
  for (int i = tid; i < 512; i += TPB) sw2[i] = gw2[i];
  if (tid < 64) sb1[tid] = gb1[tid];
  if (tid < 8) sb2[tid] = gb2[tid];
  __syncthreads();
  const int r = blockIdx.x * TPB + tid;
  float l[8];
#pragma unroll
  for (int c = 0; c < 8; c++) l[c] = sb2[c];
  const float* gr = graw + (size_t)r * 64;
  for (int k = 0; k < 64; k++) {
    const float hv = fmaxf(gr[k] + sb1[k], 0.f);
#pragma unroll
    for (int c = 0; c < 8; c++) l[c] = fmaf(hv, sw2[c * 64 + k], l[c]);
  }
  float v0 = -1e30f, v1 = -1e30f; int i0 = 0, i1 = 0;
#pragma unroll
  for (int c = 0; c < 8; c++) {
    const float lv = l[c];
    if (lv > v0) { v1 = v0; i1 = i0; v0 = lv; i0 = c; }
    else if (lv > v1) { v1 = lv; i1 = c; }
  }
  const float e1 = expf(v1 - v0);
  const float inv = 1.f / (1.f + e1);
  sel0[r] = i0; sel1[r] = i1; wt0[r] = inv; wt1[r] = e1 * inv;
  atomicAdd(&counts[i0], 1);
  atomicAdd(&counts[i1], 1);
}

// ---------------- K5: padded offsets + entry-list init ---------------------
__global__ void k_prep(int* __restrict__ hdrI, int* __restrict__ entrow)
{
  const int tid = threadIdx.x;
  if (tid == 0) {
    int run = 0;
    for (int e = 0; e < 8; e++) {
      const int c = hdrI[e];
      const int pc = (c + 31) & ~31;
      hdrI[16 + e] = pc;
      hdrI[24 + e] = run;
      run += pc;
    }
    hdrI[32] = run;
  }
  if (tid >= 8 && tid < 16) hdrI[tid] = 0;
  for (int i = tid; i < 8448; i += TPB) entrow[i] = -1;
}

// ---------------- K5b: scatter rows to expert entry lists ------------------
__global__ void k_scatter(const int* __restrict__ sel0, const int* __restrict__ sel1,
                          int* __restrict__ hdrI, int* __restrict__ entrow,
                          int* __restrict__ p0, int* __restrict__ p1)
{
  const int r = blockIdx.x * TPB + threadIdx.x;
  const int e0 = sel0[r];
  int pos = atomicAdd(&hdrI[8 + e0], 1) + hdrI[24 + e0];
  entrow[pos] = r; p0[r] = pos;
  const int e1 = sel1[r];
  pos = atomicAdd(&hdrI[8 + e1], 1) + hdrI[24 + e1];
  entrow[pos] = r; p1[r] = pos;
}

// ---------------- K6: dense MFMA fc1 -> h1 bf16 [4096][1024] ---------------
__global__ __launch_bounds__(512) void k_fc1(
    const ushort* __restrict__ featb, const ushort* __restrict__ w1b,
    const float* __restrict__ eb1, __hip_bfloat16* __restrict__ h1b)
{
  __shared__ ushort As[128 * 72];
  __shared__ ushort Bs[128 * 72];
  const int tid = threadIdx.x;
  const int r0 = blockIdx.x * 128;
  const int c0 = blockIdx.y * 128;
  const int w = tid >> 6, lane = tid & 63;
  const int wr = (w >> 1) * 32, wc = (w & 1) * 64;
  const int m = lane & 15, q = lane >> 4;
  f32x4 acc[2][4];
#pragma unroll
  for (int i = 0; i < 2; i++)
#pragma unroll
    for (int j = 0; j < 4; j++) acc[i][j] = 0.f;

  for (int kc = 0; kc < 4096; kc += 64) {
#pragma unroll
    for (int i = 0; i < 2; i++) {
      const int u = tid + 512 * i;
      const int row = u >> 3, k8 = (u & 7) * 8;
      *(uint4*)(&As[row * 72 + k8]) =
          *(const uint4*)(featb + (size_t)(r0 + row) * 4160 + kc + k8);
      *(uint4*)(&Bs[row * 72 + k8]) =
          *(const uint4*)(w1b + (size_t)(c0 + row) * 4160 + kc + k8);
    }
    __syncthreads();
#pragma unroll
    for (int kk = 0; kk < 64; kk += 32) {
      bf16x8 af[2], bf[4];
#pragma unroll
      for (int t = 0; t < 2; t++)
        af[t] = *(const bf16x8*)(&As[(wr + t * 16 + m) * 72 + kk + q * 8]);
#pragma unroll
      for (int t = 0; t < 4; t++)
        bf[t] = *(const bf16x8*)(&Bs[(wc + t * 16 + m) * 72 + kk + q * 8]);
#pragma unroll
      for (int ti = 0; ti < 2; ti++)
#pragma unroll
        for (int tj = 0; tj < 4; tj++)
          acc[ti][tj] = __builtin_amdgcn_mfma_f32_16x16x32_bf16(
              af[ti], bf[tj], acc[ti][tj], 0, 0, 0);
    }
    __syncthreads();
  }
#pragma unroll
  for (int tj = 0; tj < 4; tj++) {
    const int c = c0 + wc + tj * 16 + m;
    const float bb = eb1[c];
#pragma unroll
    for (int ti = 0; ti < 2; ti++) {
      const int rbase = r0 + wr + ti * 16 + q * 4;
#pragma unroll
      for (int i = 0; i < 4; i++) {
        const float v = fmaxf(acc[ti][tj][i] + bb, 0.f);
        h1b[(size_t)(rbase + i) * 1024 + c] = __float2bfloat16(v);
      }
    }
  }
}

// ---------------- K7: dense fc2 -> h2 fp32 [4096][512] ---------------------
__global__ __launch_bounds__(TPB) void k_fc2(
    const __hip_bfloat16* __restrict__ h1b, const float* __restrict__ ew2,
    const float* __restrict__ eb2, float* __restrict__ h2)
{
  __shared__ float h1s[64 * 132];
  __shared__ ushort w2s[128 * 72];
  const int tid = threadIdx.x;
  const int r0 = blockIdx.x * 64;
  const int e = blockIdx.y;
  const ushort* hp = (const ushort*)h1b;
#pragma unroll
  for (int i = 0; i < 4; i++) {
    const int u = tid + 256 * i;
    const int row = u >> 4, k8 = (u & 15) * 8;
    uint4 v = *(const uint4*)(hp + (size_t)(r0 + row) * 1024 + e * 128 + k8);
    const ushort* pv = (const ushort*)&v;
    float* d = &h1s[row * 132 + k8];
#pragma unroll
    for (int t = 0; t < 8; t++) d[t] = bf2f(pv[t]);
  }
#pragma unroll
  for (int i = 0; i < 8; i++) {
    const int u = tid + 256 * i;
    const int nn = u >> 5, k4 = (u & 31) * 4;
    const float4 v = *(const float4*)(ew2 + (size_t)e * 8192 + nn * 128 + k4);
    w2s[(k4 + 0) * 72 + nn] = f2b(v.x);
    w2s[(k4 + 1) * 72 + nn] = f2b(v.y);
    w2s[(k4 + 2) * 72 + nn] = f2b(v.z);
    w2s[(k4 + 3) * 72 + nn] = f2b(v.w);
  }
  __syncthreads();
  const int ty = tid >> 4, tx = tid & 15;
  float acc[4][4] = {{0.f}};
  for (int k4 = 0; k4 < 32; k4++) {
    f32x4 a4[4];
#pragma unroll
    for (int i = 0; i < 4; i++)
      a4[i] = *(const f32x4*)(&h1s[(ty * 4 + i) * 132 + k4 * 4]);
#pragma unroll
    for (int kk = 0; kk < 4; kk++) {
      const ushort4 wu = *(const ushort4*)(&w2s[(k4 * 4 + kk) * 72 + tx * 4]);
      const float w0 = bf2f(wu.x), w1 = bf2f(wu.y);
      const float w2_ = bf2f(wu.z), w3 = bf2f(wu.w);
#pragma unroll
      for (int i = 0; i < 4; i++) {
        acc[i][0] = fmaf(a4[i][kk], w0, acc[i][0]);
        acc[i][1] = fmaf(a4[i][kk], w1, acc[i][1]);
        acc[i][2] = fmaf(a4[i][kk], w2_, acc[i][2]);
        acc[i][3] = fmaf(a4[i][kk], w3, acc[i][3]);
      }
    }
  }
  const f32x4 bb = *(const f32x4*)(eb2 + e * 64 + tx * 4);
#pragma unroll
  for (int i = 0; i < 4; i++) {
    f32x4 r;
#pragma unroll
    for (int j = 0; j < 4; j++) r[j] = fmaxf(acc[i][j] + bb[j], 0.f);
    *(f32x4*)(h2 + (size_t)(r0 + ty * 4 + i) * 512 + e * 64 + tx * 4) = r;
  }
}

// ---------------- K8: grouped fc3 -> eo [pos][1000] ------------------------
__global__ __launch_bounds__(TPB) void k_fc3(
    const float* __restrict__ h2, const float* __restrict__ ew3,
    const float* __restrict__ eb3, const int* __restrict__ hdrI,
    const int* __restrict__ entrow, float* __restrict__ eo)
{
  __shared__ float h2s[32 * 68];
  __shared__ float w3s[64 * 132];
  const int e = blockIdx.y;
  const int pcnt = hdrI[16 + e];
  if ((int)blockIdx.x * 32 >= pcnt) return;
  const int base = hdrI[24 + e] + blockIdx.x * 32;
  const int tid = threadIdx.x;
  for (int i = tid; i < 512; i += TPB) {
    const int row = i >> 4, k4 = (i & 15) * 4;
    const int rr = entrow[base + row];
    f32x4 v = 0.f;
    if (rr >= 0) v = *(const f32x4*)(h2 + (size_t)rr * 512 + e * 64 + k4);
    *(f32x4*)(&h2s[row * 68 + k4]) = v;
  }
  const int ty = tid >> 5, tx = tid & 31;
  const float* w3p = ew3 + (size_t)e * 64000;
  const float* b3p = eb3 + (size_t)e * 1000;
  for (int nc = 0; nc < 8; nc++) {
    const int o0 = nc * 128;
    for (int i = tid; i < 2048; i += TPB) {
      const int oo = i >> 4, k4 = (i & 15) * 4;
      const int o = o0 + oo;
      f32x4 u = 0.f;
      if (o < 1000) u = *(const f32x4*)(w3p + (size_t)o * 64 + k4);
      w3s[(k4 + 0) * 132 + oo] = u[0];
      w3s[(k4 + 1) * 132 + oo] = u[1];
      w3s[(k4 + 2) * 132 + oo] = u[2];
      w3s[(k4 + 3) * 132 + oo] = u[3];
    }
    __syncthreads();
    float acc[4][4] = {{0.f}};
    for (int k4 = 0; k4 < 16; k4++) {
      f32x4 a4[4], w4[4];
#pragma unroll
      for (int i = 0; i < 4; i++)
        a4[i] = *(const f32x4*)(&h2s[(ty * 4 + i) * 68 + k4 * 4]);
#pragma unroll
      for (int kk = 0; kk < 4; kk++)
        w4[kk] = *(const f32x4*)(&w3s[(k4 * 4 + kk) * 132 + tx * 4]);
#pragma unroll
      for (int kk = 0; kk < 4; kk++)
#pragma unroll
        for (int i = 0; i < 4; i++)
#pragma unroll
          for (int j = 0; j < 4; j++)
            acc[i][j] = fmaf(a4[i][kk], w4[kk][j], acc[i][j]);
    }
    const int o = o0 + tx * 4;
    if (o + 3 < 1000) {
      const f32x4 bb = *(const f32x4*)(b3p + o);
#pragma unroll
      for (int i = 0; i < 4; i++) {
        f32x4 r;
#pragma unroll
        for (int j = 0; j < 4; j++) r[j] = acc[i][j] + bb[j];
        *(f32x4*)(eo + (size_t)(base + ty * 4 + i) * 1000 + o) = r;
      }
    }
    __syncthreads();
  }
}

// ---------------- K9: gate-combine + log_softmax(|.|) ----------------------
__global__ __launch_bounds__(TPB) void k_out(
    const float* __restrict__ eo, const int* __restrict__ p0,
    const int* __restrict__ p1, const float* __restrict__ wt0,
    const float* __restrict__ wt1, float* __restrict__ out)
{
  __shared__ float sv[1000];
  __shared__ float sr[8];
  const int r = blockIdx.x, tid = threadIdx.x;
  const float w0 = wt0[r], w1 = wt1[r];
  const float* a = eo + (size_t)p0[r] * 1000;
  const float* b = eo + (size_t)p1[r] * 1000;
  float lmax = -3.4e38f;
  for (int o = tid; o < 1000; o += TPB) {
    const float v = fabsf(w0 * a[o] + w1 * b[o]);
    sv[o] = v;
    lmax = fmaxf(lmax, v);
  }
#pragma unroll
  for (int off = 32; off; off >>= 1) lmax = fmaxf(lmax, __shfl_down(lmax, off));
  if ((tid & 63) == 0) sr[tid >> 6] = lmax;
  __syncthreads();
  const float mx = fmaxf(fmaxf(sr[0], sr[1]), fmaxf(sr[2], sr[3]));
  float lsum = 0.f;
  for (int o = tid; o < 1000; o += TPB) lsum += expf(sv[o] - mx);
#pragma unroll
  for (int off = 32; off; off >>= 1) lsum += __shfl_down(lsum, off);
  if ((tid & 63) == 0) sr[4 + (tid >> 6)] = lsum;
  __syncthreads();
  const float lse = logf(sr[4] + sr[5] + sr[6] + sr[7]);
  const float sub = mx + lse;
  for (int o = tid; o < 1000; o += TPB)
    out[(size_t)r * 1000 + o] = sv[o] - sub;
}

// ---------------------------------------------------------------------------
extern "C" void kernel_launch(void* const* d_in, const int* in_sizes, int n_in,
                              void* d_out, int out_size, void* d_ws, size_t ws_size,
                              hipStream_t stream)
{
  (void)in_sizes; (void)n_in; (void)out_size; (void)ws_size;
  const float* x   = (const float*)d_in[0];
  const float* c1w = (const float*)d_in[1];
  const float* c1b = (const float*)d_in[2];
  const float* bng = (const float*)d_in[3];
  const float* bnb = (const float*)d_in[4];
  const float* c2w = (const float*)d_in[5];
  const float* c2b = (const float*)d_in[6];
  const float* gw1 = (const float*)d_in[7];
  const float* gb1 = (const float*)d_in[8];
  const float* gw2 = (const float*)d_in[9];
  const float* gb2 = (const float*)d_in[10];
  const float* ew1 = (const float*)d_in[11];
  const float* eb1 = (const float*)d_in[12];
  const float* ew2 = (const float*)d_in[13];
  const float* eb2 = (const float*)d_in[14];
  const float* ew3 = (const float*)d_in[15];
  const float* eb3 = (const float*)d_in[16];

  char* ws = (char*)d_ws;
  float* statsF = (float*)ws;
  int*   hdrI   = (int*)(ws + 256);
  int*   sel0   = (int*)(ws + 1024);
  int*   sel1   = (int*)(ws + 17408);
  float* wt0    = (float*)(ws + 33792);
  float* wt1    = (float*)(ws + 50176);
  int*   p0     = (int*)(ws + 66560);
  int*   p1     = (int*)(ws + 82944);
  int*   entrow = (int*)(ws + 99328);
  float* graw   = (float*)(ws + 133120);
  float* eo     = (float*)(ws + 1181696);
  __hip_bfloat16* h1b = (__hip_bfloat16*)(ws + 34973696);
  float* h2     = (float*)(ws + 43362304);
  __hip_bfloat16* pool1 = (__hip_bfloat16*)(ws + 51750912);
  __hip_bfloat16* featb = (__hip_bfloat16*)(ws + 130476032);
  ushort* w1b   = (ushort*)(ws + 164554752);

  hipMemsetAsync(ws, 0, 512, stream);
  hipMemsetAsync(graw, 0, 4096 * 64 * sizeof(float), stream);

  k_castw1 <<<1024, TPB, 0, stream>>>(ew1, w1b);
  k_conv1  <<<4096, TPB, 0, stream>>>(x, c1w, c1b, pool1, statsF);
  k_bnfin  <<<1, 64, 0, stream>>>(bng, bnb, statsF);
  k_conv2  <<<dim3(4096, 2), TPB, 0, stream>>>(pool1, statsF, c2w, c2b, featb);
  k_gate1  <<<dim3(64, 4), TPB, 0, stream>>>((const ushort*)featb, gw1, graw);
  k_gate2  <<<16, TPB, 0, stream>>>(graw, gb1, gw2, gb2, sel0, sel1, wt0, wt1, hdrI);
  k_prep   <<<1, TPB, 0, stream>>>(hdrI, entrow);
  k_scatter<<<16, TPB, 0, stream>>>(sel0, sel1, hdrI, entrow, p0, p1);
  k_fc1    <<<dim3(32, 8), 512, 0, stream>>>((const ushort*)featb, w1b, eb1, h1b);
  k_fc2    <<<dim3(64, 8), TPB, 0, stream>>>(h1b, ew2, eb2, h2);
  k_fc3    <<<dim3(128, 8), TPB, 0, stream>>>(h2, ew3, eb3, hdrI, entrow, eo);
  k_out    <<<4096, TPB, 0, stream>>>(eo, p0, p1, wt0, wt1, (float*)d_out);
}

// Round 4
// 1283.749 us; speedup vs baseline: 1.8054x; 1.1375x over previous
//
#include <hip/hip_runtime.h>
#include <hip/hip_bf16.h>

// ---------------------------------------------------------------------------
// Net_83674552861196 — round 4: conv2 on MFMA (rolling row-im2col, 32x32x16).
//  - k_conv2: one block/image. Padded input 10x33x36 bf16 in LDS; 8 circular
//    row-slices [28 pos][72] (K=(kh | ic*5+kw), each kh-slice padded 50->64);
//    all 20 weight B-frags in VGPRs; wave w computes conv row 4i+w with a
//    20-MFMA dual chain; 2x2 pool: horizontal intra-lane (C reg pairs),
//    vertical via small LDS exchange between wave pairs; bias+relu at store.
//  - everything else unchanged from round 3.
// ---------------------------------------------------------------------------

#define TPB 256

typedef __attribute__((ext_vector_type(8))) short bf16x8;
typedef __attribute__((ext_vector_type(4))) float f32x4;
typedef __attribute__((ext_vector_type(16))) float f32x16;

__device__ __forceinline__ float bf2f(unsigned short u) {
  return __uint_as_float(((unsigned)u) << 16);
}
__device__ __forceinline__ ushort f2b(float f) {
  __hip_bfloat16 h = __float2bfloat16(f);
  return *(ushort*)&h;
}

// ---------------- K1: conv1 (MFMA) + raw-maxpool + BN statistics -----------
__global__ __launch_bounds__(TPB) void k_conv1(
    const float* __restrict__ x, const float* __restrict__ w1c,
    const float* __restrict__ b1c, __hip_bfloat16* __restrict__ pool1,
    float* __restrict__ stats)
{
  __shared__ ushort img[3 * 66 * 68];   // 26928 B
  __shared__ ushort slc[9 * 64 * 18];   // 20736 B; slot 8 = permanent zeros
  __shared__ float sred[20];
  const int tid = threadIdx.x;
  const int lane = tid & 63;
  const int w = tid >> 6;
  const int n = blockIdx.x;
  const int oc = lane & 15;
  const int q = lane >> 4;

  {
    uint* p = (uint*)img;
    for (int i = tid; i < 6732; i += TPB) p[i] = 0;
    uint* z = (uint*)slc;
    for (int i = tid; i < 5184; i += TPB) z[i] = 0;
    if (tid < 20) sred[tid] = 0.f;
  }
  __syncthreads();

  {
    const float* xp = x + (size_t)n * 12288;
#pragma unroll
    for (int it = 0; it < 12; it++) {
      const int e = 4 * (tid + 256 * it);
      const float4 v = *(const float4*)(xp + e);
      const int ic = e >> 12, rem = e & 4095, row = rem >> 6, col = rem & 63;
      ushort* d = &img[ic * 4488 + (row + 1) * 68 + (col + 1)];
      d[0] = f2b(v.x); d[1] = f2b(v.y); d[2] = f2b(v.z); d[3] = f2b(v.w);
    }
  }

  bf16x8 bfrag[3];
#pragma unroll
  for (int ch = 0; ch < 3; ch++) {
    union { ushort s[8]; bf16x8 v; } bu;
#pragma unroll
    for (int j = 0; j < 8; j++) {
      const int k15 = (q & 1) * 8 + j;
      const int kh = 2 * ch + (q >> 1);
      float wv = 0.f;
      if (oc < 10 && k15 < 15 && kh < 5) {
        const int ic = (k15 >= 10) ? 2 : ((k15 >= 5) ? 1 : 0);
        const int kw = k15 - ic * 5;
        wv = w1c[oc * 75 + ic * 25 + kh * 5 + kw];
      }
      bu.s[j] = f2b(wv);
    }
    bfrag[ch] = bu.v;
  }
  const float bias = (oc < 10) ? b1c[oc] : 0.f;

  int bsrc[4], bdst[4], bcnt = 0;
#pragma unroll
  for (int j = 0; j < 4; j++) {
    const int k15 = w + 4 * j;
    if (k15 < 15) {
      const int ic = (k15 >= 10) ? 2 : ((k15 >= 5) ? 1 : 0);
      const int kw = k15 - ic * 5;
      bsrc[bcnt] = ic * 4488 + kw + lane;
      bdst[bcnt] = lane * 18 + k15;
      bcnt++;
    }
  }

  __syncthreads();

  for (int t = 0; t < 4; t++) {
    ushort* sb = &slc[(t & 7) * 1152];
    const int tof = t * 68;
    for (int j = 0; j < bcnt; j++) sb[bdst[j]] = img[bsrc[j] + tof];
  }

  const int c0 = w * 16;
  const int fofs = (c0 + oc) * 18 + (q & 1) * 8;
  const bool qlo = (q < 2);
  float vm[4];
#pragma unroll
  for (int i = 0; i < 4; i++)
    vm[i] = ((c0 + q * 4 + i) < 62) ? 1.f : 0.f;

  float ts = 0.f, tss = 0.f;
  float pp0 = 0.f, pp1 = 0.f;

  for (int r = 0; r < 62; r++) {
    {
      const int t = r + 4;
      ushort* sb = &slc[(t & 7) * 1152];
      const int tof = t * 68;
      for (int j = 0; j < bcnt; j++) sb[bdst[j]] = img[bsrc[j] + tof];
    }
    __syncthreads();

    f32x4 acc = {0.f, 0.f, 0.f, 0.f};
#pragma unroll
    for (int ch = 0; ch < 3; ch++) {
      const int sa = (r + 2 * ch) & 7;
      const int sb2 = (ch == 2) ? 8 : ((r + 2 * ch + 1) & 7);
      const ushort* base = &slc[(qlo ? sa : sb2) * 1152 + fofs];
      union { uint u[4]; bf16x8 v; } au;
      au.u[0] = *(const uint*)(base + 0);
      au.u[1] = *(const uint*)(base + 2);
      au.u[2] = *(const uint*)(base + 4);
      au.u[3] = *(const uint*)(base + 6);
      acc = __builtin_amdgcn_mfma_f32_16x16x32_bf16(au.v, bfrag[ch], acc, 0, 0, 0);
    }

    const float y0 = acc[0] + bias, y1 = acc[1] + bias;
    const float y2 = acc[2] + bias, y3 = acc[3] + bias;
    float t0 = y0 * vm[0]; ts += t0; tss = fmaf(t0, y0, tss);
    float t1 = y1 * vm[1]; ts += t1; tss = fmaf(t1, y1, tss);
    float t2 = y2 * vm[2]; ts += t2; tss = fmaf(t2, y2, tss);
    float t3 = y3 * vm[3]; ts += t3; tss = fmaf(t3, y3, tss);
    const float p0v = fmaxf(y0, y1), p1v = fmaxf(y2, y3);
    if ((r & 1) == 0) {
      pp0 = p0v; pp1 = p1v;
    } else if (oc < 10) {
      const int ph = r >> 1;
      const int pwb = (c0 >> 1) + q * 2;
      __hip_bfloat16* dst = pool1 + (size_t)n * 9610 + (size_t)(ph * 31) * 10 + oc;
      const float q0 = fmaxf(pp0, p0v), q1 = fmaxf(pp1, p1v);
      dst[pwb * 10] = __float2bfloat16(q0);
      if (pwb + 1 < 31) dst[(pwb + 1) * 10] = __float2bfloat16(q1);
    }
  }

  if (oc < 10) {
    atomicAdd(&sred[oc], ts);
    atomicAdd(&sred[10 + oc], tss);
  }
  __syncthreads();
  if (tid < 20) atomicAdd(&stats[tid], sred[tid]);
}

// ---------------- K2: finalize BN scale/shift ------------------------------
__global__ void k_bnfin(const float* __restrict__ bng,
                        const float* __restrict__ bnb,
                        float* __restrict__ stats)
{
  const int c = threadIdx.x;
  if (c < 10) {
    const float Ninv = 1.f / (4096.f * 3844.f);
    const float mean = stats[c] * Ninv;
    const float var = stats[10 + c] * Ninv - mean * mean;
    const float sc = bng[c] * rsqrtf(var + 1e-5f);
    stats[20 + c] = sc;
    stats[30 + c] = bnb[c] - mean * sc;
  }
}

// ---------------- K3: conv2 on MFMA + pool2 -> featb -----------------------
// One block per image, 4 waves. out(r,c)=sum_{kh,ic,kw} w*img_pad[ic][r+kh][c+kw]
// GEMM view: M=pos c (28, pad 32), N=oc (20, pad 32), K=5 slices x 64 (50 real:
// j=ic*5+kw). Slice S_t[pos][j]=img_pad[ic][t][pos+kw]. Wave w does row 4i+w.
__global__ __launch_bounds__(TPB, 2) void k_conv2(
    const __hip_bfloat16* __restrict__ pool1, const float* __restrict__ stats,
    const float* __restrict__ w2c, const float* __restrict__ b2c,
    __hip_bfloat16* __restrict__ featb)
{
  __shared__ ushort img[10 * 33 * 36];   // 23760 B, padded 33x33 (stride 36)
  __shared__ ushort slc[8 * 28 * 72];    // 32256 B, j>=50 stays zero forever
  __shared__ float xbuf[2 * 20 * 17];    // cross-wave vertical pool exchange
  __shared__ float ssc[10], ssh[10];
  const int tid = threadIdx.x;
  const int w = tid >> 6, lane = tid & 63;
  const int n = blockIdx.x;
  const int oc = lane & 31;              // MFMA n index
  const int q = lane >> 5;

  for (int i = tid; i < 5940; i += TPB) ((uint*)img)[i] = 0;
  for (int i = tid; i < 8064; i += TPB) ((uint*)slc)[i] = 0;
  if (tid < 10) { ssc[tid] = stats[20 + tid]; ssh[tid] = stats[30 + tid]; }

  // weight B-frags in VGPRs (20 x 4 VGPR); lanes oc>=20 get zeros.
  bf16x8 wf[20];
#pragma unroll
  for (int kk = 0; kk < 20; kk++) {
    const int s = kk >> 2, sub = kk & 3;
    union { ushort u[8]; bf16x8 v; } bu;
#pragma unroll
    for (int i = 0; i < 8; i++) {
      const int j = sub * 16 + q * 8 + i;
      float wv = 0.f;
      if (oc < 20 && j < 50)
        wv = w2c[oc * 250 + (j / 5) * 25 + s * 5 + (j % 5)];
      bu.u[i] = f2b(wv);
    }
    wf[kk] = bu.v;
  }
  const float bias = (oc < 20) ? b2c[oc] : 0.f;

  // zero fc1 K-pad cols while we're at it
  if (tid < 120)
    *(uint*)((ushort*)featb + (size_t)n * 4160 + 3920 + 2 * tid) = 0u;

  __syncthreads();

  // stage image: BN+relu(pool1) -> padded bf16 img
  {
    const __hip_bfloat16* src = pool1 + (size_t)n * 9610;
    for (int i = tid; i < 9610; i += TPB) {
      const int p = i / 10, ic = i - p * 10;
      const int r = p / 31, c = p - r * 31;
      float v = __bfloat162float(src[i]);
      v = fmaxf(fmaf(v, ssc[ic], ssh[ic]), 0.f);
      img[ic * 1188 + (r + 1) * 36 + (c + 1)] = f2b(v);
    }
  }
  __syncthreads();

  // build slice t (whole wave): 28 pos x 10 ic, 5 els each
#define BUILD_SLICE(t)                                            \
  {                                                               \
    ushort* sb_ = &slc[((t) & 7) * 2016];                         \
    const int iof_ = (t) * 36;                                    \
    for (int it_ = 0; it_ < 5; it_++) {                           \
      const int item_ = lane + 64 * it_;                          \
      if (item_ < 280) {                                          \
        const int pos_ = item_ / 10, ic_ = item_ - pos_ * 10;     \
        const ushort* s_ = &img[ic_ * 1188 + iof_ + pos_];        \
        ushort* d_ = &sb_[pos_ * 72 + ic_ * 5];                   \
        d_[0] = s_[0]; d_[1] = s_[1]; d_[2] = s_[2];              \
        d_[3] = s_[3]; d_[4] = s_[4];                             \
      }                                                           \
    }                                                             \
  }

  BUILD_SLICE(w);
  BUILD_SLICE(w + 4);
  __syncthreads();

  const int pos_eff = (oc < 28) ? oc : oc - 16;   // lanes 28..31: garbage rows
  float hp[8];

  for (int i = 0; i < 7; i++) {
    const int r = 4 * i + w;
    f32x16 accA, accB;
#pragma unroll
    for (int z = 0; z < 16; z++) { accA[z] = 0.f; accB[z] = 0.f; }

#pragma unroll
    for (int s = 0; s < 5; s++) {
      const int slot = (r + s) & 7;
      const ushort* base = &slc[(slot * 28 + pos_eff) * 72 + q * 8];
#pragma unroll
      for (int sub = 0; sub < 4; sub++) {
        union { uint u[4]; bf16x8 v; } au;
        const ushort* pA = base + sub * 16;
        au.u[0] = *(const uint*)(pA + 0);
        au.u[1] = *(const uint*)(pA + 2);
        au.u[2] = *(const uint*)(pA + 4);
        au.u[3] = *(const uint*)(pA + 6);
        if (s & 1)
          accB = __builtin_amdgcn_mfma_f32_32x32x16_bf16(au.v, wf[s * 4 + sub], accB, 0, 0, 0);
        else
          accA = __builtin_amdgcn_mfma_f32_32x32x16_bf16(au.v, wf[s * 4 + sub], accA, 0, 0, 0);
      }
    }

    // horizontal 2x2 pool halves: C rows m=(reg&3)+8*(reg>>2)+4q; reg pairs
    // (2p,2p+1) are adjacent positions -> hp[p] at pw = P[p]+2q, P={0,1,4,5,8,9,12,13}
#pragma unroll
    for (int p = 0; p < 8; p++)
      hp[p] = fmaxf(accA[2 * p] + accB[2 * p], accA[2 * p + 1] + accB[2 * p + 1]);

    if (!(w & 1)) {                       // even wave (row 2ph): publish
      if (oc < 20) {
        float* xb = &xbuf[(w >> 1) * 340 + oc * 17 + 2 * q];
#pragma unroll
        for (int p = 0; p < 8; p++) xb[(p >> 1) * 4 + (p & 1)] = hp[p];
      }
    }
    __syncthreads();
    if (w & 1) {                          // odd wave (row 2ph+1): combine+store
      if (oc < 20) {
        const float* xb = &xbuf[(w >> 1) * 340 + oc * 17 + 2 * q];
        const int ph = 2 * i + (w >> 1);
        ushort* dst = (ushort*)featb + (size_t)n * 4160 + oc * 196 + ph * 14 + 2 * q;
#pragma unroll
        for (int p = 0; p < 8; p += 2) {
          const int pw = 2 * q + (p >> 1) * 4;
          if (pw + 1 < 14) {
            const float v0 = fmaxf(fmaxf(hp[p], xb[(p >> 1) * 4]) + bias, 0.f);
            const float v1 = fmaxf(fmaxf(hp[p + 1], xb[(p >> 1) * 4 + 1]) + bias, 0.f);
            *(uint*)(dst + (p >> 1) * 4) = (uint)f2b(v0) | ((uint)f2b(v1) << 16);
          }
        }
      }
    }
    {                                     // build next 4 slices (t<=31)
      const int t = 4 * i + 8 + w;
      if (t <= 31) BUILD_SLICE(t);
    }
    __syncthreads();
  }
#undef BUILD_SLICE
}

// ---------------- K3b: cast ew1 -> bf16 [1024][4160] -----------------------
__global__ __launch_bounds__(TPB) void k_castw1(
    const float* __restrict__ ew1, ushort* __restrict__ w1b)
{
  const int o = blockIdx.x;
  const int tid = threadIdx.x;
  const float* srow = ew1 + (size_t)o * 3920;
  ushort* drow = w1b + (size_t)o * 4160;
  for (int i = tid; i < 1040; i += TPB) {
    const int k4 = i * 4;
    ushort4 r;
    if (k4 < 3920) {
      const float4 v = *(const float4*)(srow + k4);
      r.x = f2b(v.x); r.y = f2b(v.y); r.z = f2b(v.z); r.w = f2b(v.w);
    } else {
      r.x = 0; r.y = 0; r.z = 0; r.w = 0;
    }
    *(ushort4*)(drow + k4) = r;
  }
}

// ---------------- K4a: gate fc1 partial GEMM (atomic K-split) --------------
__global__ __launch_bounds__(TPB) void k_gate1(
    const ushort* __restrict__ featb, const float* __restrict__ gw1,
    float* __restrict__ graw)
{
  __shared__ float sf[64 * 113];
  __shared__ float sw[64 * 113];
  const int tid = threadIdx.x;
  const int r0 = blockIdx.x * 64;
  const int kz = blockIdx.y;
  const int ty = tid >> 4, tx = tid & 15;
  float acc[4][4] = {{0.f}};
  for (int c = kz; c < 35; c += 4) {
    const int k0 = c * 112;
    for (int i = tid; i < 896; i += TPB) {
      const int row = i / 14, k8 = (i - row * 14) * 8;
      uint4 v = *(const uint4*)(featb + (size_t)(r0 + row) * 4160 + k0 + k8);
      const ushort* pv = (const ushort*)&v;
      float* d = &sf[row * 113 + k8];
#pragma unroll
      for (int t = 0; t < 8; t++) d[t] = bf2f(pv[t]);
    }
    for (int i = tid; i < 1792; i += TPB) {
      const int row = i / 28, c4 = (i - row * 28) * 4;
      float4 u = *(const float4*)(gw1 + (size_t)row * 3920 + k0 + c4);
      float* e = &sw[row * 113 + c4];
      e[0] = u.x; e[1] = u.y; e[2] = u.z; e[3] = u.w;
    }
    __syncthreads();
    for (int k = 0; k < 112; k++) {
      float a_[4], w_[4];
#pragma unroll
      for (int i = 0; i < 4; i++) a_[i] = sf[(ty * 4 + i) * 113 + k];
#pragma unroll
      for (int j = 0; j < 4; j++) w_[j] = sw[(tx * 4 + j) * 113 + k];
#pragma unroll
      for (int i = 0; i < 4; i++)
#pragma unroll
        for (int j = 0; j < 4; j++) acc[i][j] = fmaf(a_[i], w_[j], acc[i][j]);
    }
    __syncthreads();
  }
#pragma unroll
  for (int i = 0; i < 4; i++)
#pragma unroll
    for (int j = 0; j < 4; j++)
      atomicAdd(&graw[(size_t)(r0 + ty * 4 + i) * 64 + tx * 4 + j], acc[i][j]);
}

// ---------------- K4b: gate logits + top2 softmax + expert counts ----------
__global__ __launch_bounds__(TPB) void k_gate2(
    const float* __restrict__ graw, const float* __restrict__ gb1,
    const float* __restrict__ gw2, const float* __restrict__ gb2,
    int* __restrict__ sel0, int* __restrict__ sel1,
    float* __restrict__ wt0, float* __restrict__ wt1, int* __restrict__ counts)
{
  __shared__ float sw2[512], sb1[64], sb2[8];
  const int tid = threadIdx.x;
  for (int i = tid; i < 512; i += TPB) sw2[i] = gw2[i];
  if (tid < 64) sb1[tid] = gb1[tid];
  if (tid < 8) sb2[tid] = gb2[tid];
  __syncthreads();
  const int r = blockIdx.x * TPB + tid;
  float l[8];
#pragma unroll
  for (int c = 0; c < 8; c++) l[c] = sb2[c];
  const float* gr = graw + (size_t)r * 64;
  for (int k = 0; k < 64; k++) {
    const float hv = fmaxf(gr[k] + sb1[k], 0.f);
#pragma unroll
    for (int c = 0; c < 8; c++) l[c] = fmaf(hv, sw2[c * 64 + k], l[c]);
  }
  float v0 = -1e30f, v1 = -1e30f; int i0 = 0, i1 = 0;
#pragma unroll
  for (int c = 0; c < 8; c++) {
    const float lv = l[c];
    if (lv > v0) { v1 = v0; i1 = i0; v0 = lv; i0 = c; }
    else if (lv > v1) { v1 = lv; i1 = c; }
  }
  const float e1 = expf(v1 - v0);
  const float inv = 1.f / (1.f + e1);
  sel0[r] = i0; sel1[r] = i1; wt0[r] = inv; wt1[r] = e1 * inv;
  atomicAdd(&counts[i0], 1);
  atomicAdd(&counts[i1], 1);
}

// ---------------- K5: padded offsets + entry-list init ---------------------
__global__ void k_prep(int* __restrict__ hdrI, int* __restrict__ entrow)
{
  const int tid = threadIdx.x;
  if (tid == 0) {
    int run = 0;
    for (int e = 0; e < 8; e++) {
      const int c = hdrI[e];
      const int pc = (c + 31) & ~31;
      hdrI[16 + e] = pc;
      hdrI[24 + e] = run;
      run += pc;
    }
    hdrI[32] = run;
  }
  if (tid >= 8 && tid < 16) hdrI[tid] = 0;
  for (int i = tid; i < 8448; i += TPB) entrow[i] = -1;
}

// ---------------- K5b: scatter rows to expert entry lists ------------------
__global__ void k_scatter(const int* __restrict__ sel0, const int* __restrict__ sel1,
                          int* __restrict__ hdrI, int* __restrict__ entrow,
                          int* __restrict__ p0, int* __restrict__ p1)
{
  const int r = blockIdx.x * TPB + threadIdx.x;
  const int e0 = sel0[r];
  int pos = atomicAdd(&hdrI[8 + e0], 1) + hdrI[24 + e0];
  entrow[pos] = r; p0[r] = pos;
  const int e1 = sel1[r];
  pos = atomicAdd(&hdrI[8 + e1], 1) + hdrI[24 + e1];
  entrow[pos] = r; p1[r] = pos;
}

// ---------------- K6: dense MFMA fc1 -> h1 bf16 [4096][1024] ---------------
__global__ __launch_bounds__(512) void k_fc1(
    const ushort* __restrict__ featb, const ushort* __restrict__ w1b,
    const float* __restrict__ eb1, __hip_bfloat16* __restrict__ h1b)
{
  __shared__ ushort As[128 * 72];
  __shared__ ushort Bs[128 * 72];
  const int tid = threadIdx.x;
  const int r0 = blockIdx.x * 128;
  const int c0 = blockIdx.y * 128;
  const int w = tid >> 6, lane = tid & 63;
  const int wr = (w >> 1) * 32, wc = (w & 1) * 64;
  const int m = lane & 15, q = lane >> 4;
  f32x4 acc[2][4];
#pragma unroll
  for (int i = 0; i < 2; i++)
#pragma unroll
    for (int j = 0; j < 4; j++) acc[i][j] = 0.f;

  for (int kc = 0; kc < 4096; kc += 64) {
#pragma unroll
    for (int i = 0; i < 2; i++) {
      const int u = tid + 512 * i;
      const int row = u >> 3, k8 = (u & 7) * 8;
      *(uint4*)(&As[row * 72 + k8]) =
          *(const uint4*)(featb + (size_t)(r0 + row) * 4160 + kc + k8);
      *(uint4*)(&Bs[row * 72 + k8]) =
          *(const uint4*)(w1b + (size_t)(c0 + row) * 4160 + kc + k8);
    }
    __syncthreads();
#pragma unroll
    for (int kk = 0; kk < 64; kk += 32) {
      bf16x8 af[2], bf[4];
#pragma unroll
      for (int t = 0; t < 2; t++)
        af[t] = *(const bf16x8*)(&As[(wr + t * 16 + m) * 72 + kk + q * 8]);
#pragma unroll
      for (int t = 0; t < 4; t++)
        bf[t] = *(const bf16x8*)(&Bs[(wc + t * 16 + m) * 72 + kk + q * 8]);
#pragma unroll
      for (int ti = 0; ti < 2; ti++)
#pragma unroll
        for (int tj = 0; tj < 4; tj++)
          acc[ti][tj] = __builtin_amdgcn_mfma_f32_16x16x32_bf16(
              af[ti], bf[tj], acc[ti][tj], 0, 0, 0);
    }
    __syncthreads();
  }
#pragma unroll
  for (int tj = 0; tj < 4; tj++) {
    const int c = c0 + wc + tj * 16 + m;
    const float bb = eb1[c];
#pragma unroll
    for (int ti = 0; ti < 2; ti++) {
      const int rbase = r0 + wr + ti * 16 + q * 4;
#pragma unroll
      for (int i = 0; i < 4; i++) {
        const float v = fmaxf(acc[ti][tj][i] + bb, 0.f);
        h1b[(size_t)(rbase + i) * 1024 + c] = __float2bfloat16(v);
      }
    }
  }
}

// ---------------- K7: dense fc2 -> h2 fp32 [4096][512] ---------------------
__global__ __launch_bounds__(TPB) void k_fc2(
    const __hip_bfloat16* __restrict__ h1b, const float* __restrict__ ew2,
    const float* __restrict__ eb2, float* __restrict__ h2)
{
  __shared__ float h1s[64 * 132];
  __shared__ ushort w2s[128 * 72];
  const int tid = threadIdx.x;
  const int r0 = blockIdx.x * 64;
  const int e = blockIdx.y;
  const ushort* hp = (const ushort*)h1b;
#pragma unroll
  for (int i = 0; i < 4; i++) {
    const int u = tid + 256 * i;
    const int row = u >> 4, k8 = (u & 15) * 8;
    uint4 v = *(const uint4*)(hp + (size_t)(r0 + row) * 1024 + e * 128 + k8);
    const ushort* pv = (const ushort*)&v;
    float* d = &h1s[row * 132 + k8];
#pragma unroll
    for (int t = 0; t < 8; t++) d[t] = bf2f(pv[t]);
  }
#pragma unroll
  for (int i = 0; i < 8; i++) {
    const int u = tid + 256 * i;
    const int nn = u >> 5, k4 = (u & 31) * 4;
    const float4 v = *(const float4*)(ew2 + (size_t)e * 8192 + nn * 128 + k4);
    w2s[(k4 + 0) * 72 + nn] = f2b(v.x);
    w2s[(k4 + 1) * 72 + nn] = f2b(v.y);
    w2s[(k4 + 2) * 72 + nn] = f2b(v.z);
    w2s[(k4 + 3) * 72 + nn] = f2b(v.w);
  }
  __syncthreads();
  const int ty = tid >> 4, tx = tid & 15;
  float acc[4][4] = {{0.f}};
  for (int k4 = 0; k4 < 32; k4++) {
    f32x4 a4[4];
#pragma unroll
    for (int i = 0; i < 4; i++)
      a4[i] = *(const f32x4*)(&h1s[(ty * 4 + i) * 132 + k4 * 4]);
#pragma unroll
    for (int kk = 0; kk < 4; kk++) {
      const ushort4 wu = *(const ushort4*)(&w2s[(k4 * 4 + kk) * 72 + tx * 4]);
      const float w0 = bf2f(wu.x), w1 = bf2f(wu.y);
      const float w2_ = bf2f(wu.z), w3 = bf2f(wu.w);
#pragma unroll
      for (int i = 0; i < 4; i++) {
        acc[i][0] = fmaf(a4[i][kk], w0, acc[i][0]);
        acc[i][1] = fmaf(a4[i][kk], w1, acc[i][1]);
        acc[i][2] = fmaf(a4[i][kk], w2_, acc[i][2]);
        acc[i][3] = fmaf(a4[i][kk], w3, acc[i][3]);
      }
    }
  }
  const f32x4 bb = *(const f32x4*)(eb2 + e * 64 + tx * 4);
#pragma unroll
  for (int i = 0; i < 4; i++) {
    f32x4 r;
#pragma unroll
    for (int j = 0; j < 4; j++) r[j] = fmaxf(acc[i][j] + bb[j], 0.f);
    *(f32x4*)(h2 + (size_t)(r0 + ty * 4 + i) * 512 + e * 64 + tx * 4) = r;
  }
}

// ---------------- K8: grouped fc3 -> eo [pos][1000] ------------------------
__global__ __launch_bounds__(TPB) void k_fc3(
    const float* __restrict__ h2, const float* __restrict__ ew3,
    const float* __restrict__ eb3, const int* __restrict__ hdrI,
    const int* __restrict__ entrow, float* __restrict__ eo)
{
  __shared__ float h2s[32 * 68];
  __shared__ float w3s[64 * 132];
  const int e = blockIdx.y;
  const int pcnt = hdrI[16 + e];
  if ((int)blockIdx.x * 32 >= pcnt) return;
  const int base = hdrI[24 + e] + blockIdx.x * 32;
  const int tid = threadIdx.x;
  for (int i = tid; i < 512; i += TPB) {
    const int row = i >> 4, k4 = (i & 15) * 4;
    const int rr = entrow[base + row];
    f32x4 v = 0.f;
    if (rr >= 0) v = *(const f32x4*)(h2 + (size_t)rr * 512 + e * 64 + k4);
    *(f32x4*)(&h2s[row * 68 + k4]) = v;
  }
  const int ty = tid >> 5, tx = tid & 31;
  const float* w3p = ew3 + (size_t)e * 64000;
  const float* b3p = eb3 + (size_t)e * 1000;
  for (int nc = 0; nc < 8; nc++) {
    const int o0 = nc * 128;
    for (int i = tid; i < 2048; i += TPB) {
      const int oo = i >> 4, k4 = (i & 15) * 4;
      const int o = o0 + oo;
      f32x4 u = 0.f;
      if (o < 1000) u = *(const f32x4*)(w3p + (size_t)o * 64 + k4);
      w3s[(k4 + 0) * 132 + oo] = u[0];
      w3s[(k4 + 1) * 132 + oo] = u[1];
      w3s[(k4 + 2) * 132 + oo] = u[2];
      w3s[(k4 + 3) * 132 + oo] = u[3];
    }
    __syncthreads();
    float acc[4][4] = {{0.f}};
    for (int k4 = 0; k4 < 16; k4++) {
      f32x4 a4[4], w4[4];
#pragma unroll
      for (int i = 0; i < 4; i++)
        a4[i] = *(const f32x4*)(&h2s[(ty * 4 + i) * 68 + k4 * 4]);
#pragma unroll
      for (int kk = 0; kk < 4; kk++)
        w4[kk] = *(const f32x4*)(&w3s[(k4 * 4 + kk) * 132 + tx * 4]);
#pragma unroll
      for (int kk = 0; kk < 4; kk++)
#pragma unroll
        for (int i = 0; i < 4; i++)
#pragma unroll
          for (int j = 0; j < 4; j++)
            acc[i][j] = fmaf(a4[i][kk], w4[kk][j], acc[i][j]);
    }
    const int o = o0 + tx * 4;
    if (o + 3 < 1000) {
      const f32x4 bb = *(const f32x4*)(b3p + o);
#pragma unroll
      for (int i = 0; i < 4; i++) {
        f32x4 r;
#pragma unroll
        for (int j = 0; j < 4; j++) r[j] = acc[i][j] + bb[j];
        *(f32x4*)(eo + (size_t)(base + ty * 4 + i) * 1000 + o) = r;
      }
    }
    __syncthreads();
  }
}

// ---------------- K9: gate-combine + log_softmax(|.|) ----------------------
__global__ __launch_bounds__(TPB) void k_out(
    const float* __restrict__ eo, const int* __restrict__ p0,
    const int* __restrict__ p1, const float* __restrict__ wt0,
    const float* __restrict__ wt1, float* __restrict__ out)
{
  __shared__ float sv[1000];
  __shared__ float sr[8];
  const int r = blockIdx.x, tid = threadIdx.x;
  const float w0 = wt0[r], w1 = wt1[r];
  const float* a = eo + (size_t)p0[r] * 1000;
  const float* b = eo + (size_t)p1[r] * 1000;
  float lmax = -3.4e38f;
  for (int o = tid; o < 1000; o += TPB) {
    const float v = fabsf(w0 * a[o] + w1 * b[o]);
    sv[o] = v;
    lmax = fmaxf(lmax, v);
  }
#pragma unroll
  for (int off = 32; off; off >>= 1) lmax = fmaxf(lmax, __shfl_down(lmax, off));
  if ((tid & 63) == 0) sr[tid >> 6] = lmax;
  __syncthreads();
  const float mx = fmaxf(fmaxf(sr[0], sr[1]), fmaxf(sr[2], sr[3]));
  float lsum = 0.f;
  for (int o = tid; o < 1000; o += TPB) lsum += expf(sv[o] - mx);
#pragma unroll
  for (int off = 32; off; off >>= 1) lsum += __shfl_down(lsum, off);
  if ((tid & 63) == 0) sr[4 + (tid >> 6)] = lsum;
  __syncthreads();
  const float lse = logf(sr[4] + sr[5] + sr[6] + sr[7]);
  const float sub = mx + lse;
  for (int o = tid; o < 1000; o += TPB)
    out[(size_t)r * 1000 + o] = sv[o] - sub;
}

// ---------------------------------------------------------------------------
extern "C" void kernel_launch(void* const* d_in, const int* in_sizes, int n_in,
                              void* d_out, int out_size, void* d_ws, size_t ws_size,
                              hipStream_t stream)
{
  (void)in_sizes; (void)n_in; (void)out_size; (void)ws_size;
  const float* x   = (const float*)d_in[0];
  const float* c1w = (const float*)d_in[1];
  const float* c1b = (const float*)d_in[2];
  const float* bng = (const float*)d_in[3];
  const float* bnb = (const float*)d_in[4];
  const float* c2w = (const float*)d_in[5];
  const float* c2b = (const float*)d_in[6];
  const float* gw1 = (const float*)d_in[7];
  const float* gb1 = (const float*)d_in[8];
  const float* gw2 = (const float*)d_in[9];
  const float* gb2 = (const float*)d_in[10];
  const float* ew1 = (const float*)d_in[11];
  const float* eb1 = (const float*)d_in[12];
  const float* ew2 = (const float*)d_in[13];
  const float* eb2 = (const float*)d_in[14];
  const float* ew3 = (const float*)d_in[15];
  const float* eb3 = (const float*)d_in[16];

  char* ws = (char*)d_ws;
  float* statsF = (float*)ws;
  int*   hdrI   = (int*)(ws + 256);
  int*   sel0   = (int*)(ws + 1024);
  int*   sel1   = (int*)(ws + 17408);
  float* wt0    = (float*)(ws + 33792);
  float* wt1    = (float*)(ws + 50176);
  int*   p0     = (int*)(ws + 66560);
  int*   p1     = (int*)(ws + 82944);
  int*   entrow = (int*)(ws + 99328);
  float* graw   = (float*)(ws + 133120);
  float* eo     = (float*)(ws + 1181696);
  __hip_bfloat16* h1b = (__hip_bfloat16*)(ws + 34973696);
  float* h2     = (float*)(ws + 43362304);
  __hip_bfloat16* pool1 = (__hip_bfloat16*)(ws + 51750912);
  __hip_bfloat16* featb = (__hip_bfloat16*)(ws + 130476032);
  ushort* w1b   = (ushort*)(ws + 164554752);

  hipMemsetAsync(ws, 0, 512, stream);
  hipMemsetAsync(graw, 0, 4096 * 64 * sizeof(float), stream);

  k_castw1 <<<1024, TPB, 0, stream>>>(ew1, w1b);
  k_conv1  <<<4096, TPB, 0, stream>>>(x, c1w, c1b, pool1, statsF);
  k_bnfin  <<<1, 64, 0, stream>>>(bng, bnb, statsF);
  k_conv2  <<<4096, TPB, 0, stream>>>(pool1, statsF, c2w, c2b, featb);
  k_gate1  <<<dim3(64, 4), TPB, 0, stream>>>((const ushort*)featb, gw1, graw);
  k_gate2  <<<16, TPB, 0, stream>>>(graw, gb1, gw2, gb2, sel0, sel1, wt0, wt1, hdrI);
  k_prep   <<<1, TPB, 0, stream>>>(hdrI, entrow);
  k_scatter<<<16, TPB, 0, stream>>>(sel0, sel1, hdrI, entrow, p0, p1);
  k_fc1    <<<dim3(32, 8), 512, 0, stream>>>((const ushort*)featb, w1b, eb1, h1b);
  k_fc2    <<<dim3(64, 8), TPB, 0, stream>>>(h1b, ew2, eb2, h2);
  k_fc3    <<<dim3(128, 8), TPB, 0, stream>>>(h2, ew3, eb3, hdrI, entrow, eo);
  k_out    <<<4096, TPB, 0, stream>>>(eo, p0, p1, wt0, wt1, (float*)d_out);
}

// Round 5
// 1074.016 us; speedup vs baseline: 2.1579x; 1.1953x over previous
//
#include <hip/hip_runtime.h>
#include <hip/hip_bf16.h>

// ---------------------------------------------------------------------------
// Net_83674552861196 — round 5: barrier-free conv2 (one image per WAVE).
//  - K-order j=kw*10+ic makes im2col rows contiguous in pool1's [pw][ic]
//    layout: A[pos][j] = Row[r+kh][pos*10+j]. No slice building.
//  - Per wave: rolling 4-slot LDS row buffer (344 els/row); 5 kh A-frag sets
//    cached in registers (rotate mod 5, loop unrolled by 5); 20 weight
//    B-frags in VGPRs; K-pad j>=50 killed by zero B. Global row loads
//    pipelined one iteration ahead. Vertical+horizontal 2x2 pool fully
//    in-register (same wave does consecutive rows). Zero __syncthreads in
//    the main loop; per-wave s_waitcnt lgkmcnt(0) only.
//  - everything else unchanged from round 4.
// ---------------------------------------------------------------------------

#define TPB 256

typedef __attribute__((ext_vector_type(8))) short bf16x8;
typedef __attribute__((ext_vector_type(4))) float f32x4;
typedef __attribute__((ext_vector_type(16))) float f32x16;

__device__ __forceinline__ float bf2f(unsigned short u) {
  return __uint_as_float(((unsigned)u) << 16);
}
__device__ __forceinline__ ushort f2b(float f) {
  __hip_bfloat16 h = __float2bfloat16(f);
  return *(ushort*)&h;
}

// ---------------- K1: conv1 (MFMA) + raw-maxpool + BN statistics -----------
__global__ __launch_bounds__(TPB) void k_conv1(
    const float* __restrict__ x, const float* __restrict__ w1c,
    const float* __restrict__ b1c, __hip_bfloat16* __restrict__ pool1,
    float* __restrict__ stats)
{
  __shared__ ushort img[3 * 66 * 68];   // 26928 B
  __shared__ ushort slc[9 * 64 * 18];   // 20736 B; slot 8 = permanent zeros
  __shared__ float sred[20];
  const int tid = threadIdx.x;
  const int lane = tid & 63;
  const int w = tid >> 6;
  const int n = blockIdx.x;
  const int oc = lane & 15;
  const int q = lane >> 4;

  {
    uint* p = (uint*)img;
    for (int i = tid; i < 6732; i += TPB) p[i] = 0;
    uint* z = (uint*)slc;
    for (int i = tid; i < 5184; i += TPB) z[i] = 0;
    if (tid < 20) sred[tid] = 0.f;
  }
  __syncthreads();

  {
    const float* xp = x + (size_t)n * 12288;
#pragma unroll
    for (int it = 0; it < 12; it++) {
      const int e = 4 * (tid + 256 * it);
      const float4 v = *(const float4*)(xp + e);
      const int ic = e >> 12, rem = e & 4095, row = rem >> 6, col = rem & 63;
      ushort* d = &img[ic * 4488 + (row + 1) * 68 + (col + 1)];
      d[0] = f2b(v.x); d[1] = f2b(v.y); d[2] = f2b(v.z); d[3] = f2b(v.w);
    }
  }

  bf16x8 bfrag[3];
#pragma unroll
  for (int ch = 0; ch < 3; ch++) {
    union { ushort s[8]; bf16x8 v; } bu;
#pragma unroll
    for (int j = 0; j < 8; j++) {
      const int k15 = (q & 1) * 8 + j;
      const int kh = 2 * ch + (q >> 1);
      float wv = 0.f;
      if (oc < 10 && k15 < 15 && kh < 5) {
        const int ic = (k15 >= 10) ? 2 : ((k15 >= 5) ? 1 : 0);
        const int kw = k15 - ic * 5;
        wv = w1c[oc * 75 + ic * 25 + kh * 5 + kw];
      }
      bu.s[j] = f2b(wv);
    }
    bfrag[ch] = bu.v;
  }
  const float bias = (oc < 10) ? b1c[oc] : 0.f;

  int bsrc[4], bdst[4], bcnt = 0;
#pragma unroll
  for (int j = 0; j < 4; j++) {
    const int k15 = w + 4 * j;
    if (k15 < 15) {
      const int ic = (k15 >= 10) ? 2 : ((k15 >= 5) ? 1 : 0);
      const int kw = k15 - ic * 5;
      bsrc[bcnt] = ic * 4488 + kw + lane;
      bdst[bcnt] = lane * 18 + k15;
      bcnt++;
    }
  }

  __syncthreads();

  for (int t = 0; t < 4; t++) {
    ushort* sb = &slc[(t & 7) * 1152];
    const int tof = t * 68;
    for (int j = 0; j < bcnt; j++) sb[bdst[j]] = img[bsrc[j] + tof];
  }

  const int c0 = w * 16;
  const int fofs = (c0 + oc) * 18 + (q & 1) * 8;
  const bool qlo = (q < 2);
  float vm[4];
#pragma unroll
  for (int i = 0; i < 4; i++)
    vm[i] = ((c0 + q * 4 + i) < 62) ? 1.f : 0.f;

  float ts = 0.f, tss = 0.f;
  float pp0 = 0.f, pp1 = 0.f;

  for (int r = 0; r < 62; r++) {
    {
      const int t = r + 4;
      ushort* sb = &slc[(t & 7) * 1152];
      const int tof = t * 68;
      for (int j = 0; j < bcnt; j++) sb[bdst[j]] = img[bsrc[j] + tof];
    }
    __syncthreads();

    f32x4 acc = {0.f, 0.f, 0.f, 0.f};
#pragma unroll
    for (int ch = 0; ch < 3; ch++) {
      const int sa = (r + 2 * ch) & 7;
      const int sb2 = (ch == 2) ? 8 : ((r + 2 * ch + 1) & 7);
      const ushort* base = &slc[(qlo ? sa : sb2) * 1152 + fofs];
      union { uint u[4]; bf16x8 v; } au;
      au.u[0] = *(const uint*)(base + 0);
      au.u[1] = *(const uint*)(base + 2);
      au.u[2] = *(const uint*)(base + 4);
      au.u[3] = *(const uint*)(base + 6);
      acc = __builtin_amdgcn_mfma_f32_16x16x32_bf16(au.v, bfrag[ch], acc, 0, 0, 0);
    }

    const float y0 = acc[0] + bias, y1 = acc[1] + bias;
    const float y2 = acc[2] + bias, y3 = acc[3] + bias;
    float t0 = y0 * vm[0]; ts += t0; tss = fmaf(t0, y0, tss);
    float t1 = y1 * vm[1]; ts += t1; tss = fmaf(t1, y1, tss);
    float t2 = y2 * vm[2]; ts += t2; tss = fmaf(t2, y2, tss);
    float t3 = y3 * vm[3]; ts += t3; tss = fmaf(t3, y3, tss);
    const float p0v = fmaxf(y0, y1), p1v = fmaxf(y2, y3);
    if ((r & 1) == 0) {
      pp0 = p0v; pp1 = p1v;
    } else if (oc < 10) {
      const int ph = r >> 1;
      const int pwb = (c0 >> 1) + q * 2;
      __hip_bfloat16* dst = pool1 + (size_t)n * 9610 + (size_t)(ph * 31) * 10 + oc;
      const float q0 = fmaxf(pp0, p0v), q1 = fmaxf(pp1, p1v);
      dst[pwb * 10] = __float2bfloat16(q0);
      if (pwb + 1 < 31) dst[(pwb + 1) * 10] = __float2bfloat16(q1);
    }
  }

  if (oc < 10) {
    atomicAdd(&sred[oc], ts);
    atomicAdd(&sred[10 + oc], tss);
  }
  __syncthreads();
  if (tid < 20) atomicAdd(&stats[tid], sred[tid]);
}

// ---------------- K2: finalize BN scale/shift ------------------------------
__global__ void k_bnfin(const float* __restrict__ bng,
                        const float* __restrict__ bnb,
                        float* __restrict__ stats)
{
  const int c = threadIdx.x;
  if (c < 10) {
    const float Ninv = 1.f / (4096.f * 3844.f);
    const float mean = stats[c] * Ninv;
    const float var = stats[10 + c] * Ninv - mean * mean;
    const float sc = bng[c] * rsqrtf(var + 1e-5f);
    stats[20 + c] = sc;
    stats[30 + c] = bnb[c] - mean * sc;
  }
}

// ---------------- K3: conv2 on MFMA, one image per wave --------------------
// out(r,pos,oc) = sum_{kh} sum_{j<50, j=kw*10+ic} Row[r+kh][pos*10+j] * W[oc][j,kh]
// Row[t][u] (u=pw_pad*10+ic) = BN-relu(pool1[n][t-1][pw_pad-1][ic]), zero borders.
// M=pos(28,pad32), N=oc(20,pad32), K=5 x 64 (j>=50 has zero B).
__global__ __launch_bounds__(TPB, 2) void k_conv2(
    const __hip_bfloat16* __restrict__ pool1, const float* __restrict__ stats,
    const float* __restrict__ w2c, const float* __restrict__ b2c,
    __hip_bfloat16* __restrict__ featb)
{
  __shared__ ushort R[4][4][344];          // [wave-image][slot][u], 11 KB
  __shared__ float ssc[10], ssh[10];
  const int tid = threadIdx.x;
  const int w = tid >> 6, lane = tid & 63;
  const int n = blockIdx.x * 4 + w;
  const int pos = lane & 31, q = lane >> 5;
  ushort (*Rw)[344] = R[w];

  if (tid < 10) { ssc[tid] = stats[20 + tid]; ssh[tid] = stats[30 + tid]; }
  // zero border cols of own 4 slots: u in [0,10) and [320,344)
  for (int i = lane; i < 136; i += 64) {
    const int s = i / 34, uu = i - 34 * s;
    Rw[s][(uu < 10) ? uu : (310 + uu)] = 0;
  }
  // zero fc1 K-pad cols for this image
  if (lane < 60) {
    uint* z = (uint*)((ushort*)featb + (size_t)n * 4160 + 3920);
    z[lane] = 0; z[lane + 60] = 0;
  }
  __syncthreads();

  // weight B-frags in VGPRs (j = kw*10+ic)
  bf16x8 wf[20];
#pragma unroll
  for (int kk = 0; kk < 20; kk++) {
    union { ushort u[8]; bf16x8 v; } bu;
    const int s = kk >> 2;
#pragma unroll
    for (int i = 0; i < 8; i++) {
      const int j = (kk & 3) * 16 + q * 8 + i;
      float wv = 0.f;
      if ((pos < 20) && (j < 50))
        wv = w2c[pos * 250 + (j % 10) * 25 + s * 5 + (j / 10)];
      bu.u[i] = f2b(wv);
    }
    wf[kk] = bu.v;
  }
  const float bias = (pos < 20) ? b2c[pos] : 0.f;

  const ushort* pp = (const ushort*)pool1 + (size_t)n * 9610;
  const int ic0 = (2 * lane) % 10;
  const int pos_e = (pos < 28) ? pos : pos - 16;
  const int pe10q8 = pos_e * 10 + q * 8;

  uint gv0, gv1, gv2;
#define GLOAD(t)                                                        \
  {                                                                     \
    const ushort* s_ = pp + ((t) - 1) * 310;                            \
    gv0 = *(const uint*)(s_ + 2 * lane);                                \
    gv1 = *(const uint*)(s_ + 2 * (lane + 64));                         \
    gv2 = (lane < 27) ? *(const uint*)(s_ + 2 * (lane + 128)) : 0u;     \
  }
#define GS1(c_, gv_)                                                    \
  {                                                                     \
    const int u2_ = lane + 64 * c_;                                     \
    if (c_ < 2 || lane < 27) {                                          \
      const int ia_ = (ic0 + 8 * c_) % 10;                              \
      const int ib_ = (ia_ == 9) ? 0 : ia_ + 1;                         \
      float a0_ = bf2f((ushort)(gv_ & 0xffffu));                        \
      float a1_ = bf2f((ushort)(gv_ >> 16));                            \
      a0_ = fmaxf(fmaf(a0_, ssc[ia_], ssh[ia_]), 0.f);                  \
      a1_ = fmaxf(fmaf(a1_, ssc[ib_], ssh[ib_]), 0.f);                  \
      *(uint*)(dst_ + 2 * u2_) = (uint)f2b(a0_) | ((uint)f2b(a1_) << 16);\
    }                                                                   \
  }
#define GSTORE(t)                                                       \
  {                                                                     \
    ushort* dst_ = &Rw[(t) & 3][10];                                    \
    GS1(0, gv0) GS1(1, gv1) GS1(2, gv2)                                 \
  }
#define FLOAD(t, ss)                                                    \
  {                                                                     \
    const ushort* bp_ = &Rw[(t) & 3][pe10q8];                           \
    _Pragma("unroll")                                                   \
    for (int sub_ = 0; sub_ < 4; sub_++) {                              \
      union { uint u[4]; bf16x8 v; } au_;                               \
      au_.u[0] = *(const uint*)(bp_ + sub_ * 16 + 0);                   \
      au_.u[1] = *(const uint*)(bp_ + sub_ * 16 + 2);                   \
      au_.u[2] = *(const uint*)(bp_ + sub_ * 16 + 4);                   \
      au_.u[3] = *(const uint*)(bp_ + sub_ * 16 + 6);                   \
      sets[ss][sub_] = au_.v;                                           \
    }                                                                   \
  }

  bf16x8 sets[5][4];
  const bf16x8 zfrag = (short)0;
#pragma unroll
  for (int s = 0; s < 4; s++) sets[0][s] = zfrag;   // t=0 border row

  GLOAD(1) GSTORE(1)
  GLOAD(2) GSTORE(2)
  GLOAD(3) GSTORE(3)
  GLOAD(4) GSTORE(4)
  GLOAD(5)
  __asm__ __volatile__("s_waitcnt lgkmcnt(0)" ::: "memory");
  FLOAD(1, 1) FLOAD(2, 2) FLOAD(3, 3)

  float php[8];
  for (int rb = 0; rb < 30; rb += 5) {
#pragma unroll
    for (int rr = 0; rr < 5; rr++) {
      const int r = rb + rr;
      __asm__ __volatile__("s_waitcnt lgkmcnt(0)" ::: "memory");
      if (r <= 27) FLOAD(r + 4, (rr + 4) % 5)
      if (r <= 26) GSTORE(r + 5)
      if (r <= 25) GLOAD(r + 6)
      if (r < 28) {
        f32x16 accA, accB;
#pragma unroll
        for (int z = 0; z < 16; z++) { accA[z] = 0.f; accB[z] = 0.f; }
#pragma unroll
        for (int kh = 0; kh < 5; kh++) {
          const int si = (rr + kh) % 5;
#pragma unroll
          for (int sub = 0; sub < 4; sub++) {
            if (kh & 1)
              accB = __builtin_amdgcn_mfma_f32_32x32x16_bf16(
                  sets[si][sub], wf[kh * 4 + sub], accB, 0, 0, 0);
            else
              accA = __builtin_amdgcn_mfma_f32_32x32x16_bf16(
                  sets[si][sub], wf[kh * 4 + sub], accA, 0, 0, 0);
          }
        }
        float hp[8];
#pragma unroll
        for (int p = 0; p < 8; p++)
          hp[p] = fmaxf(accA[2 * p] + accB[2 * p],
                        accA[2 * p + 1] + accB[2 * p + 1]);
        if ((r & 1) == 0) {
#pragma unroll
          for (int p = 0; p < 8; p++) php[p] = hp[p];
        } else if (pos < 20) {
          const int ph = r >> 1;
          ushort* dst = (ushort*)featb + (size_t)n * 4160 + pos * 196 + ph * 14;
#pragma unroll
          for (int j = 0; j < 4; j++) {
            const int pw = 4 * j + 2 * q;
            if (pw + 1 < 14) {
              const float v0 =
                  fmaxf(fmaxf(php[2 * j], hp[2 * j]) + bias, 0.f);
              const float v1 =
                  fmaxf(fmaxf(php[2 * j + 1], hp[2 * j + 1]) + bias, 0.f);
              *(uint*)(dst + pw) = (uint)f2b(v0) | ((uint)f2b(v1) << 16);
            }
          }
        }
      }
    }
  }
#undef GLOAD
#undef GS1
#undef GSTORE
#undef FLOAD
}

// ---------------- K3b: cast ew1 -> bf16 [1024][4160] -----------------------
__global__ __launch_bounds__(TPB) void k_castw1(
    const float* __restrict__ ew1, ushort* __restrict__ w1b)
{
  const int o = blockIdx.x;
  const int tid = threadIdx.x;
  const float* srow = ew1 + (size_t)o * 3920;
  ushort* drow = w1b + (size_t)o * 4160;
  for (int i = tid; i < 1040; i += TPB) {
    const int k4 = i * 4;
    ushort4 r;
    if (k4 < 3920) {
      const float4 v = *(const float4*)(srow + k4);
      r.x = f2b(v.x); r.y = f2b(v.y); r.z = f2b(v.z); r.w = f2b(v.w);
    } else {
      r.x = 0; r.y = 0; r.z = 0; r.w = 0;
    }
    *(ushort4*)(drow + k4) = r;
  }
}

// ---------------- K4a: gate fc1 partial GEMM (atomic K-split) --------------
__global__ __launch_bounds__(TPB) void k_gate1(
    const ushort* __restrict__ featb, const float* __restrict__ gw1,
    float* __restrict__ graw)
{
  __shared__ float sf[64 * 113];
  __shared__ float sw[64 * 113];
  const int tid = threadIdx.x;
  const int r0 = blockIdx.x * 64;
  const int kz = blockIdx.y;
  const int ty = tid >> 4, tx = tid & 15;
  float acc[4][4] = {{0.f}};
  for (int c = kz; c < 35; c += 4) {
    const int k0 = c * 112;
    for (int i = tid; i < 896; i += TPB) {
      const int row = i / 14, k8 = (i - row * 14) * 8;
      uint4 v = *(const uint4*)(featb + (size_t)(r0 + row) * 4160 + k0 + k8);
      const ushort* pv = (const ushort*)&v;
      float* d = &sf[row * 113 + k8];
#pragma unroll
      for (int t = 0; t < 8; t++) d[t] = bf2f(pv[t]);
    }
    for (int i = tid; i < 1792; i += TPB) {
      const int row = i / 28, c4 = (i - row * 28) * 4;
      float4 u = *(const float4*)(gw1 + (size_t)row * 3920 + k0 + c4);
      float* e = &sw[row * 113 + c4];
      e[0] = u.x; e[1] = u.y; e[2] = u.z; e[3] = u.w;
    }
    __syncthreads();
    for (int k = 0; k < 112; k++) {
      float a_[4], w_[4];
#pragma unroll
      for (int i = 0; i < 4; i++) a_[i] = sf[(ty * 4 + i) * 113 + k];
#pragma unroll
      for (int j = 0; j < 4; j++) w_[j] = sw[(tx * 4 + j) * 113 + k];
#pragma unroll
      for (int i = 0; i < 4; i++)
#pragma unroll
        for (int j = 0; j < 4; j++) acc[i][j] = fmaf(a_[i], w_[j], acc[i][j]);
    }
    __syncthreads();
  }
#pragma unroll
  for (int i = 0; i < 4; i++)
#pragma unroll
    for (int j = 0; j < 4; j++)
      atomicAdd(&graw[(size_t)(r0 + ty * 4 + i) * 64 + tx * 4 + j], acc[i][j]);
}

// ---------------- K4b: gate logits + top2 softmax + expert counts ----------
__global__ __launch_bounds__(TPB) void k_gate2(
    const float* __restrict__ graw, const float* __restrict__ gb1,
    const float* __restrict__ gw2, const float* __restrict__ gb2,
    int* __restrict__ sel0, int* __restrict__ sel1,
    float* __restrict__ wt0, float* __restrict__ wt1, int* __restrict__ counts)
{
  __shared__ float sw2[512], sb1[64], sb2[8];
  const int tid = threadIdx.x;
  for (int i = tid; i < 512; i += TPB) sw2[i] = gw2[i];
  if (tid < 64) sb1[tid] = gb1[tid];
  if (tid < 8) sb2[tid] = gb2[tid];
  __syncthreads();
  const int r = blockIdx.x * TPB + tid;
  float l[8];
#pragma unroll
  for (int c = 0; c < 8; c++) l[c] = sb2[c];
  const float* gr = graw + (size_t)r * 64;
  for (int k = 0; k < 64; k++) {
    const float hv = fmaxf(gr[k] + sb1[k], 0.f);
#pragma unroll
    for (int c = 0; c < 8; c++) l[c] = fmaf(hv, sw2[c * 64 + k], l[c]);
  }
  float v0 = -1e30f, v1 = -1e30f; int i0 = 0, i1 = 0;
#pragma unroll
  for (int c = 0; c < 8; c++) {
    const float lv = l[c];
    if (lv > v0) { v1 = v0; i1 = i0; v0 = lv; i0 = c; }
    else if (lv > v1) { v1 = lv; i1 = c; }
  }
  const float e1 = expf(v1 - v0);
  const float inv = 1.f / (1.f + e1);
  sel0[r] = i0; sel1[r] = i1; wt0[r] = inv; wt1[r] = e1 * inv;
  atomicAdd(&counts[i0], 1);
  atomicAdd(&counts[i1], 1);
}

// ---------------- K5: padded offsets + entry-list init ---------------------
__global__ void k_prep(int* __restrict__ hdrI, int* __restrict__ entrow)
{
  const int tid = threadIdx.x;
  if (tid == 0) {
    int run = 0;
    for (int e = 0; e < 8; e++) {
      const int c = hdrI[e];
      const int pc = (c + 31) & ~31;
      hdrI[16 + e] = pc;
      hdrI[24 + e] = run;
      run += pc;
    }
    hdrI[32] = run;
  }
  if (tid >= 8 && tid < 16) hdrI[tid] = 0;
  for (int i = tid; i < 8448; i += TPB) entrow[i] = -1;
}

// ---------------- K5b: scatter rows to expert entry lists ------------------
__global__ void k_scatter(const int* __restrict__ sel0, const int* __restrict__ sel1,
                          int* __restrict__ hdrI, int* __restrict__ entrow,
                          int* __restrict__ p0, int* __restrict__ p1)
{
  const int r = blockIdx.x * TPB + threadIdx.x;
  const int e0 = sel0[r];
  int pos = atomicAdd(&hdrI[8 + e0], 1) + hdrI[24 + e0];
  entrow[pos] = r; p0[r] = pos;
  const int e1 = sel1[r];
  pos = atomicAdd(&hdrI[8 + e1], 1) + hdrI[24 + e1];
  entrow[pos] = r; p1[r] = pos;
}

// ---------------- K6: dense MFMA fc1 -> h1 bf16 [4096][1024] ---------------
__global__ __launch_bounds__(512) void k_fc1(
    const ushort* __restrict__ featb, const ushort* __restrict__ w1b,
    const float* __restrict__ eb1, __hip_bfloat16* __restrict__ h1b)
{
  __shared__ ushort As[128 * 72];
  __shared__ ushort Bs[128 * 72];
  const int tid = threadIdx.x;
  const int r0 = blockIdx.x * 128;
  const int c0 = blockIdx.y * 128;
  const int w = tid >> 6, lane = tid & 63;
  const int wr = (w >> 1) * 32, wc = (w & 1) * 64;
  const int m = lane & 15, q = lane >> 4;
  f32x4 acc[2][4];
#pragma unroll
  for (int i = 0; i < 2; i++)
#pragma unroll
    for (int j = 0; j < 4; j++) acc[i][j] = 0.f;

  for (int kc = 0; kc < 4096; kc += 64) {
#pragma unroll
    for (int i = 0; i < 2; i++) {
      const int u = tid + 512 * i;
      const int row = u >> 3, k8 = (u & 7) * 8;
      *(uint4*)(&As[row * 72 + k8]) =
          *(const uint4*)(featb + (size_t)(r0 + row) * 4160 + kc + k8);
      *(uint4*)(&Bs[row * 72 + k8]) =
          *(const uint4*)(w1b + (size_t)(c0 + row) * 4160 + kc + k8);
    }
    __syncthreads();
#pragma unroll
    for (int kk = 0; kk < 64; kk += 32) {
      bf16x8 af[2], bf[4];
#pragma unroll
      for (int t = 0; t < 2; t++)
        af[t] = *(const bf16x8*)(&As[(wr + t * 16 + m) * 72 + kk + q * 8]);
#pragma unroll
      for (int t = 0; t < 4; t++)
        bf[t] = *(const bf16x8*)(&Bs[(wc + t * 16 + m) * 72 + kk + q * 8]);
#pragma unroll
      for (int ti = 0; ti < 2; ti++)
#pragma unroll
        for (int tj = 0; tj < 4; tj++)
          acc[ti][tj] = __builtin_amdgcn_mfma_f32_16x16x32_bf16(
              af[ti], bf[tj], acc[ti][tj], 0, 0, 0);
    }
    __syncthreads();
  }
#pragma unroll
  for (int tj = 0; tj < 4; tj++) {
    const int c = c0 + wc + tj * 16 + m;
    const float bb = eb1[c];
#pragma unroll
    for (int ti = 0; ti < 2; ti++) {
      const int rbase = r0 + wr + ti * 16 + q * 4;
#pragma unroll
      for (int i = 0; i < 4; i++) {
        const float v = fmaxf(acc[ti][tj][i] + bb, 0.f);
        h1b[(size_t)(rbase + i) * 1024 + c] = __float2bfloat16(v);
      }
    }
  }
}

// ---------------- K7: dense fc2 -> h2 fp32 [4096][512] ---------------------
__global__ __launch_bounds__(TPB) void k_fc2(
    const __hip_bfloat16* __restrict__ h1b, const float* __restrict__ ew2,
    const float* __restrict__ eb2, float* __restrict__ h2)
{
  __shared__ float h1s[64 * 132];
  __shared__ ushort w2s[128 * 72];
  const int tid = threadIdx.x;
  const int r0 = blockIdx.x * 64;
  const int e = blockIdx.y;
  const ushort* hp = (const ushort*)h1b;
#pragma unroll
  for (int i = 0; i < 4; i++) {
    const int u = tid + 256 * i;
    const int row = u >> 4, k8 = (u & 15) * 8;
    uint4 v = *(const uint4*)(hp + (size_t)(r0 + row) * 1024 + e * 128 + k8);
    const ushort* pv = (const ushort*)&v;
    float* d = &h1s[row * 132 + k8];
#pragma unroll
    for (int t = 0; t < 8; t++) d[t] = bf2f(pv[t]);
  }
#pragma unroll
  for (int i = 0; i < 8; i++) {
    const int u = tid + 256 * i;
    const int nn = u >> 5, k4 = (u & 31) * 4;
    const float4 v = *(const float4*)(ew2 + (size_t)e * 8192 + nn * 128 + k4);
    w2s[(k4 + 0) * 72 + nn] = f2b(v.x);
    w2s[(k4 + 1) * 72 + nn] = f2b(v.y);
    w2s[(k4 + 2) * 72 + nn] = f2b(v.z);
    w2s[(k4 + 3) * 72 + nn] = f2b(v.w);
  }
  __syncthreads();
  const int ty = tid >> 4, tx = tid & 15;
  float acc[4][4] = {{0.f}};
  for (int k4 = 0; k4 < 32; k4++) {
    f32x4 a4[4];
#pragma unroll
    for (int i = 0; i < 4; i++)
      a4[i] = *(const f32x4*)(&h1s[(ty * 4 + i) * 132 + k4 * 4]);
#pragma unroll
    for (int kk = 0; kk < 4; kk++) {
      const ushort4 wu = *(const ushort4*)(&w2s[(k4 * 4 + kk) * 72 + tx * 4]);
      const float w0 = bf2f(wu.x), w1 = bf2f(wu.y);
      const float w2_ = bf2f(wu.z), w3 = bf2f(wu.w);
#pragma unroll
      for (int i = 0; i < 4; i++) {
        acc[i][0] = fmaf(a4[i][kk], w0, acc[i][0]);
        acc[i][1] = fmaf(a4[i][kk], w1, acc[i][1]);
        acc[i][2] = fmaf(a4[i][kk], w2_, acc[i][2]);
        acc[i][3] = fmaf(a4[i][kk], w3, acc[i][3]);
      }
    }
  }
  const f32x4 bb = *(const f32x4*)(eb2 + e * 64 + tx * 4);
#pragma unroll
  for (int i = 0; i < 4; i++) {
    f32x4 r;
#pragma unroll
    for (int j = 0; j < 4; j++) r[j] = fmaxf(acc[i][j] + bb[j], 0.f);
    *(f32x4*)(h2 + (size_t)(r0 + ty * 4 + i) * 512 + e * 64 + tx * 4) = r;
  }
}

// ---------------- K8: grouped fc3 -> eo [pos][1000] ------------------------
__global__ __launch_bounds__(TPB) void k_fc3(
    const float* __restrict__ h2, const float* __restrict__ ew3,
    const float* __restrict__ eb3, const int* __restrict__ hdrI,
    const int* __restrict__ entrow, float* __restrict__ eo)
{
  __shared__ float h2s[32 * 68];
  __shared__ float w3s[64 * 132];
  const int e = blockIdx.y;
  const int pcnt = hdrI[16 + e];
  if ((int)blockIdx.x * 32 >= pcnt) return;
  const int base = hdrI[24 + e] + blockIdx.x * 32;
  const int tid = threadIdx.x;
  for (int i = tid; i < 512; i += TPB) {
    const int row = i >> 4, k4 = (i & 15) * 4;
    const int rr = entrow[base + row];
    f32x4 v = 0.f;
    if (rr >= 0) v = *(const f32x4*)(h2 + (size_t)rr * 512 + e * 64 + k4);
    *(f32x4*)(&h2s[row * 68 + k4]) = v;
  }
  const int ty = tid >> 5, tx = tid & 31;
  const float* w3p = ew3 + (size_t)e * 64000;
  const float* b3p = eb3 + (size_t)e * 1000;
  for (int nc = 0; nc < 8; nc++) {
    const int o0 = nc * 128;
    for (int i = tid; i < 2048; i += TPB) {
      const int oo = i >> 4, k4 = (i & 15) * 4;
      const int o = o0 + oo;
      f32x4 u = 0.f;
      if (o < 1000) u = *(const f32x4*)(w3p + (size_t)o * 64 + k4);
      w3s[(k4 + 0) * 132 + oo] = u[0];
      w3s[(k4 + 1) * 132 + oo] = u[1];
      w3s[(k4 + 2) * 132 + oo] = u[2];
      w3s[(k4 + 3) * 132 + oo] = u[3];
    }
    __syncthreads();
    float acc[4][4] = {{0.f}};
    for (int k4 = 0; k4 < 16; k4++) {
      f32x4 a4[4], w4[4];
#pragma unroll
      for (int i = 0; i < 4; i++)
        a4[i] = *(const f32x4*)(&h2s[(ty * 4 + i) * 68 + k4 * 4]);
#pragma unroll
      for (int kk = 0; kk < 4; kk++)
        w4[kk] = *(const f32x4*)(&w3s[(k4 * 4 + kk) * 132 + tx * 4]);
#pragma unroll
      for (int kk = 0; kk < 4; kk++)
#pragma unroll
        for (int i = 0; i < 4; i++)
#pragma unroll
          for (int j = 0; j < 4; j++)
            acc[i][j] = fmaf(a4[i][kk], w4[kk][j], acc[i][j]);
    }
    const int o = o0 + tx * 4;
    if (o + 3 < 1000) {
      const f32x4 bb = *(const f32x4*)(b3p + o);
#pragma unroll
      for (int i = 0; i < 4; i++) {
        f32x4 r;
#pragma unroll
        for (int j = 0; j < 4; j++) r[j] = acc[i][j] + bb[j];
        *(f32x4*)(eo + (size_t)(base + ty * 4 + i) * 1000 + o) = r;
      }
    }
    __syncthreads();
  }
}

// ---------------- K9: gate-combine + log_softmax(|.|) ----------------------
__global__ __launch_bounds__(TPB) void k_out(
    const float* __restrict__ eo, const int* __restrict__ p0,
    const int* __restrict__ p1, const float* __restrict__ wt0,
    const float* __restrict__ wt1, float* __restrict__ out)
{
  __shared__ float sv[1000];
  __shared__ float sr[8];
  const int r = blockIdx.x, tid = threadIdx.x;
  const float w0 = wt0[r], w1 = wt1[r];
  const float* a = eo + (size_t)p0[r] * 1000;
  const float* b = eo + (size_t)p1[r] * 1000;
  float lmax = -3.4e38f;
  for (int o = tid; o < 1000; o += TPB) {
    const float v = fabsf(w0 * a[o] + w1 * b[o]);
    sv[o] = v;
    lmax = fmaxf(lmax, v);
  }
#pragma unroll
  for (int off = 32; off; off >>= 1) lmax = fmaxf(lmax, __shfl_down(lmax, off));
  if ((tid & 63) == 0) sr[tid >> 6] = lmax;
  __syncthreads();
  const float mx = fmaxf(fmaxf(sr[0], sr[1]), fmaxf(sr[2], sr[3]));
  float lsum = 0.f;
  for (int o = tid; o < 1000; o += TPB) lsum += expf(sv[o] - mx);
#pragma unroll
  for (int off = 32; off; off >>= 1) lsum += __shfl_down(lsum, off);
  if ((tid & 63) == 0) sr[4 + (tid >> 6)] = lsum;
  __syncthreads();
  const float lse = logf(sr[4] + sr[5] + sr[6] + sr[7]);
  const float sub = mx + lse;
  for (int o = tid; o < 1000; o += TPB)
    out[(size_t)r * 1000 + o] = sv[o] - sub;
}

// ---------------------------------------------------------------------------
extern "C" void kernel_launch(void* const* d_in, const int* in_sizes, int n_in,
                              void* d_out, int out_size, void* d_ws, size_t ws_size,
                              hipStream_t stream)
{
  (void)in_sizes; (void)n_in; (void)out_size; (void)ws_size;
  const float* x   = (const float*)d_in[0];
  const float* c1w = (const float*)d_in[1];
  const float* c1b = (const float*)d_in[2];
  const float* bng = (const float*)d_in[3];
  const float* bnb = (const float*)d_in[4];
  const float* c2w = (const float*)d_in[5];
  const float* c2b = (const float*)d_in[6];
  const float* gw1 = (const float*)d_in[7];
  const float* gb1 = (const float*)d_in[8];
  const float* gw2 = (const float*)d_in[9];
  const float* gb2 = (const float*)d_in[10];
  const float* ew1 = (const float*)d_in[11];
  const float* eb1 = (const float*)d_in[12];
  const float* ew2 = (const float*)d_in[13];
  const float* eb2 = (const float*)d_in[14];
  const float* ew3 = (const float*)d_in[15];
  const float* eb3 = (const float*)d_in[16];

  char* ws = (char*)d_ws;
  float* statsF = (float*)ws;
  int*   hdrI   = (int*)(ws + 256);
  int*   sel0   = (int*)(ws + 1024);
  int*   sel1   = (int*)(ws + 17408);
  float* wt0    = (float*)(ws + 33792);
  float* wt1    = (float*)(ws + 50176);
  int*   p0     = (int*)(ws + 66560);
  int*   p1     = (int*)(ws + 82944);
  int*   entrow = (int*)(ws + 99328);
  float* graw   = (float*)(ws + 133120);
  float* eo     = (float*)(ws + 1181696);
  __hip_bfloat16* h1b = (__hip_bfloat16*)(ws + 34973696);
  float* h2     = (float*)(ws + 43362304);
  __hip_bfloat16* pool1 = (__hip_bfloat16*)(ws + 51750912);
  __hip_bfloat16* featb = (__hip_bfloat16*)(ws + 130476032);
  ushort* w1b   = (ushort*)(ws + 164554752);

  hipMemsetAsync(ws, 0, 512, stream);
  hipMemsetAsync(graw, 0, 4096 * 64 * sizeof(float), stream);

  k_castw1 <<<1024, TPB, 0, stream>>>(ew1, w1b);
  k_conv1  <<<4096, TPB, 0, stream>>>(x, c1w, c1b, pool1, statsF);
  k_bnfin  <<<1, 64, 0, stream>>>(bng, bnb, statsF);
  k_conv2  <<<1024, TPB, 0, stream>>>(pool1, statsF, c2w, c2b, featb);
  k_gate1  <<<dim3(64, 4), TPB, 0, stream>>>((const ushort*)featb, gw1, graw);
  k_gate2  <<<16, TPB, 0, stream>>>(graw, gb1, gw2, gb2, sel0, sel1, wt0, wt1, hdrI);
  k_prep   <<<1, TPB, 0, stream>>>(hdrI, entrow);
  k_scatter<<<16, TPB, 0, stream>>>(sel0, sel1, hdrI, entrow, p0, p1);
  k_fc1    <<<dim3(32, 8), 512, 0, stream>>>((const ushort*)featb, w1b, eb1, h1b);
  k_fc2    <<<dim3(64, 8), TPB, 0, stream>>>(h1b, ew2, eb2, h2);
  k_fc3    <<<dim3(128, 8), TPB, 0, stream>>>(h2, ew3, eb3, hdrI, entrow, eo);
  k_out    <<<4096, TPB, 0, stream>>>(eo, p0, p1, wt0, wt1, (float*)d_out);
}